// Round 1
// baseline (7439.628 us; speedup 1.0000x reference)
//
#include <hip/hip_runtime.h>
#include <math.h>

#define NEG_SLOPE 0.2f

// ---------------- GEMM: C = act(A[MxK] @ B[KxN] + bias) ----------------
// 64x64 tile, BK=16, 256 threads, 4x4 microtile per thread. fp32 baseline.
#define BM 64
#define BN 64
#define BK 16

template<int ACT>  // 0=none, 1=relu, 2=elu
__global__ __launch_bounds__(256) void gemm_bias_act(
    const float* __restrict__ A, const float* __restrict__ B,
    const float* __restrict__ bias, float* __restrict__ C,
    int M, int K, int N)
{
    // As padded +4: store addr = kk*68 + r -> banks (4*kk + r)%32, 2-way max (free),
    // and 68 floats = 272 B keeps 16B alignment for float4-able reads.
    __shared__ float As[BK][BM + 4];
    __shared__ float Bs[BK][BN];
    const int tid = threadIdx.x;
    const int tx = tid & 15, ty = tid >> 4;
    const int m0 = blockIdx.y * BM;
    const int n0 = blockIdx.x * BN;
    float acc[4][4] = {};
    for (int k0 = 0; k0 < K; k0 += BK) {
#pragma unroll
        for (int it = 0; it < 4; ++it) {
            int idx = tid + it * 256;
            int r = idx >> 4, kk = idx & 15;
            int gm = m0 + r, gk = k0 + kk;
            As[kk][r] = (gm < M && gk < K) ? A[(long)gm * K + gk] : 0.f;
        }
#pragma unroll
        for (int it = 0; it < 4; ++it) {
            int idx = tid + it * 256;
            int kk = idx >> 6, nn = idx & 63;
            int gk = k0 + kk, gn = n0 + nn;
            Bs[kk][nn] = (gk < K && gn < N) ? B[(long)gk * N + gn] : 0.f;
        }
        __syncthreads();
#pragma unroll
        for (int kk = 0; kk < BK; ++kk) {
            float a[4], b[4];
#pragma unroll
            for (int i = 0; i < 4; ++i) a[i] = As[kk][ty * 4 + i];
#pragma unroll
            for (int j = 0; j < 4; ++j) b[j] = Bs[kk][tx * 4 + j];
#pragma unroll
            for (int i = 0; i < 4; ++i)
#pragma unroll
                for (int j = 0; j < 4; ++j)
                    acc[i][j] = fmaf(a[i], b[j], acc[i][j]);
        }
        __syncthreads();
    }
#pragma unroll
    for (int i = 0; i < 4; ++i) {
        int gm = m0 + ty * 4 + i;
        if (gm >= M) continue;
#pragma unroll
        for (int j = 0; j < 4; ++j) {
            int gn = n0 + tx * 4 + j;  // N is always a multiple of 64 here
            float v = acc[i][j] + (bias ? bias[gn] : 0.f);
            if (ACT == 1) v = fmaxf(v, 0.f);
            if (ACT == 2) v = v > 0.f ? v : expm1f(v);
            C[(long)gm * N + gn] = v;
        }
    }
}

// ---------------- GAT attention scalars: as[i]=x[i].a_src, ad[i]=x[i].a_dst ----
__global__ __launch_bounds__(256) void att_scalars(
    const float* __restrict__ x, const float* __restrict__ avs,
    const float* __restrict__ avd, float* __restrict__ outs,
    float* __restrict__ outd, int F)
{
    const int i = blockIdx.x;
    const int t = threadIdx.x;
    float ps = 0.f, pd = 0.f;
    for (int f = t; f < F; f += 256) {
        float v = x[(long)i * F + f];
        ps += v * avs[f];
        pd += v * avd[f];
    }
#pragma unroll
    for (int off = 32; off; off >>= 1) {
        ps += __shfl_down(ps, off);
        pd += __shfl_down(pd, off);
    }
    __shared__ float ls[4], ld[4];
    int lane = t & 63, w = t >> 6;
    if (lane == 0) { ls[w] = ps; ld[w] = pd; }
    __syncthreads();
    if (t == 0) {
        outs[i] = ls[0] + ls[1] + ls[2] + ls[3];
        outd[i] = ld[0] + ld[1] + ld[2] + ld[3];
    }
}

// ------------- float <-> monotonic uint key (for atomicMax on floats) --------
__device__ __forceinline__ unsigned fkey(float f) {
    unsigned u = __float_as_uint(f);
    return (u & 0x80000000u) ? ~u : (u | 0x80000000u);
}
__device__ __forceinline__ float unfkey(unsigned k) {
    unsigned u = (k & 0x80000000u) ? (k ^ 0x80000000u) : ~k;
    return __uint_as_float(u);
}

__device__ __forceinline__ float lrelu(float v) {
    return v > 0.f ? v : NEG_SLOPE * v;
}

// edge id t < E: real edge (src[t], dst[t]); t >= E: self loop (t-E, t-E)
__global__ __launch_bounds__(256) void edge_max_kernel(
    const int* __restrict__ src, const int* __restrict__ dst,
    const float* __restrict__ as_, const float* __restrict__ ad_,
    unsigned* __restrict__ mkey, int E, int n)
{
    int t = blockIdx.x * 256 + threadIdx.x;
    int tot = E + n;
    if (t >= tot) return;
    int s = t < E ? src[t] : (t - E);
    int d = t < E ? dst[t] : (t - E);
    float e = lrelu(as_[s] + ad_[d]);
    atomicMax(&mkey[d], fkey(e));
}

__global__ __launch_bounds__(256) void edge_denom_kernel(
    const int* __restrict__ src, const int* __restrict__ dst,
    const float* __restrict__ as_, const float* __restrict__ ad_,
    const unsigned* __restrict__ mkey, float* __restrict__ denom, int E, int n)
{
    int t = blockIdx.x * 256 + threadIdx.x;
    int tot = E + n;
    if (t >= tot) return;
    int s = t < E ? src[t] : (t - E);
    int d = t < E ? dst[t] : (t - E);
    float e = lrelu(as_[s] + ad_[d]);
    atomicAdd(&denom[d], expf(e - unfkey(mkey[d])));
}

// one wave per edge; lanes scatter alpha * x[src][f] into out[dst][f]
__global__ __launch_bounds__(256) void edge_agg_kernel(
    const int* __restrict__ src, const int* __restrict__ dst,
    const float* __restrict__ as_, const float* __restrict__ ad_,
    const unsigned* __restrict__ mkey, const float* __restrict__ denom,
    const float* __restrict__ x, float* __restrict__ out, int E, int n, int F)
{
    int gw = blockIdx.x * 4 + (threadIdx.x >> 6);
    int lane = threadIdx.x & 63;
    int tot = E + n;
    if (gw >= tot) return;
    int s = gw < E ? src[gw] : (gw - E);
    int d = gw < E ? dst[gw] : (gw - E);
    float e = lrelu(as_[s] + ad_[d]);
    float alpha = expf(e - unfkey(mkey[d])) / denom[d];
    const float* xs = x + (long)s * F;
    float* od = out + (long)d * F;
    for (int f = lane * 4; f < F; f += 256) {
        float4 v = *(const float4*)(xs + f);
        atomicAdd(od + f + 0, alpha * v.x);
        atomicAdd(od + f + 1, alpha * v.y);
        atomicAdd(od + f + 2, alpha * v.z);
        atomicAdd(od + f + 3, alpha * v.w);
    }
}

// in-place x = relu(x + b[f])  (F power of two)
__global__ __launch_bounds__(256) void bias_relu_kernel(
    float* __restrict__ x, const float* __restrict__ b, long total, int Fmask)
{
    long t = (long)blockIdx.x * 256 + threadIdx.x;
    if (t >= total) return;
    x[t] = fmaxf(x[t] + b[(int)(t & Fmask)], 0.f);
}

// comb[i] = concat(dfin[didx[i]], cfin[cidx[i]])  (256 + 256)
__global__ __launch_bounds__(256) void gather_concat_kernel(
    const float* __restrict__ dfin, const float* __restrict__ cfin,
    const int* __restrict__ didx, const int* __restrict__ cidx,
    float* __restrict__ comb)
{
    int i = blockIdx.x;
    int t = threadIdx.x;
    int ds = didx[i], cs = cidx[i];
    comb[(long)i * 512 + t] = dfin[(long)ds * 256 + t];
    comb[(long)i * 512 + 256 + t] = cfin[(long)cs * 256 + t];
}

// out[i] = h[i] . w + b[0]   (one wave per row, F=512)
__global__ __launch_bounds__(256) void head_final_kernel(
    const float* __restrict__ h, const float* __restrict__ w,
    const float* __restrict__ b, float* __restrict__ out, int M)
{
    int gw = blockIdx.x * 4 + (threadIdx.x >> 6);
    int lane = threadIdx.x & 63;
    if (gw >= M) return;
    const float* row = h + (long)gw * 512;
    float s = 0.f;
#pragma unroll
    for (int f = lane; f < 512; f += 64) s += row[f] * w[f];
#pragma unroll
    for (int off = 32; off; off >>= 1) s += __shfl_down(s, off);
    if (lane == 0) out[gw] = s + b[0];
}

// ------------------------------ orchestration -------------------------------
static inline dim3 gemm_grid(int M, int N) { return dim3(N / 64, (M + 63) / 64); }

extern "C" void kernel_launch(void* const* d_in, const int* in_sizes, int n_in,
                              void* d_out, int out_size, void* d_ws, size_t ws_size,
                              hipStream_t stream)
{
    const float* drug_x = (const float*)d_in[0];
    const float* cell_x = (const float*)d_in[1];
    const int* d_ei = (const int*)d_in[2];
    const int* c_ei = (const int*)d_in[3];
    const int* d_idx = (const int*)d_in[4];
    const int* c_idx = (const int*)d_in[5];
    const float* dW1 = (const float*)d_in[6];
    const float* db1 = (const float*)d_in[7];
    const float* cW1 = (const float*)d_in[8];
    const float* cb1 = (const float*)d_in[9];
    const float* cW2 = (const float*)d_in[10];
    const float* cb2 = (const float*)d_in[11];
    const float* gdW = (const float*)d_in[12];
    const float* gdas = (const float*)d_in[13];
    const float* gdad = (const float*)d_in[14];
    const float* gdb = (const float*)d_in[15];
    const float* g1W = (const float*)d_in[16];
    const float* g1as = (const float*)d_in[17];
    const float* g1ad = (const float*)d_in[18];
    const float* g1b = (const float*)d_in[19];
    const float* g2W = (const float*)d_in[20];
    const float* g2as = (const float*)d_in[21];
    const float* g2ad = (const float*)d_in[22];
    const float* g2b = (const float*)d_in[23];
    const float* rW1 = (const float*)d_in[24];
    const float* rb1 = (const float*)d_in[25];
    const float* rW2 = (const float*)d_in[26];
    const float* rb2 = (const float*)d_in[27];
    const float* rW3 = (const float*)d_in[28];
    const float* rb3 = (const float*)d_in[29];

    const int ND = in_sizes[0] / 128;     // 50000
    const int NC = in_sizes[1] / 735;     // 10000
    const int ED = in_sizes[2] / 2;       // 800000
    const int EC = in_sizes[3] / 2;       // 160000
    const int NB = in_sizes[4];           // 16384

    const int* d_src = d_ei;
    const int* d_dst = d_ei + ED;
    const int* c_src = c_ei;
    const int* c_dst = c_ei + EC;

    const size_t MB = 1ull << 20;
    char* ws = (char*)d_ws;
    // arena: s0 [0,52MB) | s1 [52,104) | s2 [104,156) | small [156,157)
    float* s0 = (float*)(ws);
    float* s1 = (float*)(ws + 52 * MB);
    float* s2 = (float*)(ws + 104 * MB);
    float* cG2 = (float*)(ws + 11 * MB);  // inside s0, after xc2 (9.77 MiB)
    float* small = (float*)(ws + 156 * MB);
    float* as_ = small;
    float* ad_ = small + 65536;
    unsigned* mk = (unsigned*)(small + 2 * 65536);
    float* dn = small + 3 * 65536;

    // ---------------- drug path ----------------
    // d0 = relu(drug_x @ dW1 + db1)  -> s0  [ND,256]
    gemm_bias_act<1><<<gemm_grid(ND, 256), 256, 0, stream>>>(drug_x, dW1, db1, s0, ND, 128, 256);
    // xd = d0 @ gdW -> s1  [ND,256]
    gemm_bias_act<0><<<gemm_grid(ND, 256), 256, 0, stream>>>(s0, gdW, nullptr, s1, ND, 256, 256);
    att_scalars<<<ND, 256, 0, stream>>>(s1, gdas, gdad, as_, ad_, 256);
    hipMemsetAsync(mk, 0, (size_t)ND * 4, stream);
    hipMemsetAsync(dn, 0, (size_t)ND * 4, stream);
    hipMemsetAsync(s2, 0, (size_t)ND * 256 * 4, stream);
    {
        int tot = ED + ND;
        edge_max_kernel<<<(tot + 255) / 256, 256, 0, stream>>>(d_src, d_dst, as_, ad_, mk, ED, ND);
        edge_denom_kernel<<<(tot + 255) / 256, 256, 0, stream>>>(d_src, d_dst, as_, ad_, mk, dn, ED, ND);
        edge_agg_kernel<<<(tot + 3) / 4, 256, 0, stream>>>(d_src, d_dst, as_, ad_, mk, dn, s1, s2, ED, ND, 256);
    }
    bias_relu_kernel<<<(int)(((long)ND * 256 + 255) / 256), 256, 0, stream>>>(s2, gdb, (long)ND * 256, 255);
    // d_final = s2

    // ---------------- cell path ----------------
    // c0 = relu(cell_x @ cW1 + cb1) -> s0  [NC,1024]
    gemm_bias_act<1><<<gemm_grid(NC, 1024), 256, 0, stream>>>(cell_x, cW1, cb1, s0, NC, 735, 1024);
    // c1 = relu(c0 @ cW2 + cb2) -> s1  [NC,256]
    gemm_bias_act<1><<<gemm_grid(NC, 256), 256, 0, stream>>>(s0, cW2, cb2, s1, NC, 1024, 256);
    // xc1 = c1 @ g1W -> s0  [NC,1024]
    gemm_bias_act<0><<<gemm_grid(NC, 1024), 256, 0, stream>>>(s1, g1W, nullptr, s0, NC, 256, 1024);
    att_scalars<<<NC, 256, 0, stream>>>(s0, g1as, g1ad, as_, ad_, 1024);
    hipMemsetAsync(mk, 0, (size_t)NC * 4, stream);
    hipMemsetAsync(dn, 0, (size_t)NC * 4, stream);
    hipMemsetAsync(s1, 0, (size_t)NC * 1024 * 4, stream);
    {
        int tot = EC + NC;
        edge_max_kernel<<<(tot + 255) / 256, 256, 0, stream>>>(c_src, c_dst, as_, ad_, mk, EC, NC);
        edge_denom_kernel<<<(tot + 255) / 256, 256, 0, stream>>>(c_src, c_dst, as_, ad_, mk, dn, EC, NC);
        edge_agg_kernel<<<(tot + 3) / 4, 256, 0, stream>>>(c_src, c_dst, as_, ad_, mk, dn, s0, s1, EC, NC, 1024);
    }
    bias_relu_kernel<<<(int)(((long)NC * 1024 + 255) / 256), 256, 0, stream>>>(s1, g1b, (long)NC * 1024, 1023);
    // c2 = s1 [NC,1024]
    // xc2 = c2 @ g2W -> s0  [NC,256]
    gemm_bias_act<0><<<gemm_grid(NC, 256), 256, 0, stream>>>(s1, g2W, nullptr, s0, NC, 1024, 256);
    att_scalars<<<NC, 256, 0, stream>>>(s0, g2as, g2ad, as_, ad_, 256);
    hipMemsetAsync(mk, 0, (size_t)NC * 4, stream);
    hipMemsetAsync(dn, 0, (size_t)NC * 4, stream);
    hipMemsetAsync(cG2, 0, (size_t)NC * 256 * 4, stream);
    {
        int tot = EC + NC;
        edge_max_kernel<<<(tot + 255) / 256, 256, 0, stream>>>(c_src, c_dst, as_, ad_, mk, EC, NC);
        edge_denom_kernel<<<(tot + 255) / 256, 256, 0, stream>>>(c_src, c_dst, as_, ad_, mk, dn, EC, NC);
        edge_agg_kernel<<<(tot + 3) / 4, 256, 0, stream>>>(c_src, c_dst, as_, ad_, mk, dn, s0, cG2, EC, NC, 256);
    }
    bias_relu_kernel<<<(int)(((long)NC * 256 + 255) / 256), 256, 0, stream>>>(cG2, g2b, (long)NC * 256, 255);
    // c_final = cG2

    // ---------------- head ----------------
    // comb -> s1 [NB,512]
    gather_concat_kernel<<<NB, 256, 0, stream>>>(s2, cG2, d_idx, c_idx, s1);
    // h1 = elu(comb @ rW1 + rb1) -> s2
    gemm_bias_act<2><<<gemm_grid(NB, 512), 256, 0, stream>>>(s1, rW1, rb1, s2, NB, 512, 512);
    // h2 = elu(h1 @ rW2 + rb2) -> s0
    gemm_bias_act<2><<<gemm_grid(NB, 512), 256, 0, stream>>>(s2, rW2, rb2, s0, NB, 512, 512);
    // out = h2 @ rW3 + rb3
    head_final_kernel<<<(NB + 3) / 4, 256, 0, stream>>>(s0, rW3, rb3, (float*)d_out, NB);
}

// Round 2
// 2101.474 us; speedup vs baseline: 3.5402x; 3.5402x over previous
//
#include <hip/hip_runtime.h>
#include <math.h>

#define NEG_SLOPE 0.2f

// ---------------- GEMM: C = act(A[MxK] @ B[KxN] + bias) ----------------
// 64x64 tile, BK=16, 256 threads, 4x4 microtile per thread. fp32 baseline.
#define BM 64
#define BN 64
#define BK 16

template<int ACT>  // 0=none, 1=relu, 2=elu
__global__ __launch_bounds__(256) void gemm_bias_act(
    const float* __restrict__ A, const float* __restrict__ B,
    const float* __restrict__ bias, float* __restrict__ C,
    int M, int K, int N)
{
    // As padded +4: row stride 68 floats = 272 B (16B aligned, 2-way bank alias max).
    __shared__ float As[BK][BM + 4];
    __shared__ float Bs[BK][BN];
    const int tid = threadIdx.x;
    const int tx = tid & 15, ty = tid >> 4;
    const int m0 = blockIdx.y * BM;
    const int n0 = blockIdx.x * BN;
    float acc[4][4] = {};
    for (int k0 = 0; k0 < K; k0 += BK) {
#pragma unroll
        for (int it = 0; it < 4; ++it) {
            int idx = tid + it * 256;
            int r = idx >> 4, kk = idx & 15;
            int gm = m0 + r, gk = k0 + kk;
            As[kk][r] = (gm < M && gk < K) ? A[(long)gm * K + gk] : 0.f;
        }
#pragma unroll
        for (int it = 0; it < 4; ++it) {
            int idx = tid + it * 256;
            int kk = idx >> 6, nn = idx & 63;
            int gk = k0 + kk, gn = n0 + nn;
            Bs[kk][nn] = (gk < K && gn < N) ? B[(long)gk * N + gn] : 0.f;
        }
        __syncthreads();
#pragma unroll
        for (int kk = 0; kk < BK; ++kk) {
            float4 a = *(const float4*)&As[kk][ty * 4];
            float4 b = *(const float4*)&Bs[kk][tx * 4];
            float av[4] = {a.x, a.y, a.z, a.w};
            float bv[4] = {b.x, b.y, b.z, b.w};
#pragma unroll
            for (int i = 0; i < 4; ++i)
#pragma unroll
                for (int j = 0; j < 4; ++j)
                    acc[i][j] = fmaf(av[i], bv[j], acc[i][j]);
        }
        __syncthreads();
    }
#pragma unroll
    for (int i = 0; i < 4; ++i) {
        int gm = m0 + ty * 4 + i;
        if (gm >= M) continue;
#pragma unroll
        for (int j = 0; j < 4; ++j) {
            int gn = n0 + tx * 4 + j;  // N is always a multiple of 64 here
            float v = acc[i][j] + (bias ? bias[gn] : 0.f);
            if (ACT == 1) v = fmaxf(v, 0.f);
            if (ACT == 2) v = v > 0.f ? v : expm1f(v);
            C[(long)gm * N + gn] = v;
        }
    }
}

// ---------------- GAT attention scalars: as[i]=x[i].a_src, ad[i]=x[i].a_dst ----
__global__ __launch_bounds__(256) void att_scalars(
    const float* __restrict__ x, const float* __restrict__ avs,
    const float* __restrict__ avd, float* __restrict__ outs,
    float* __restrict__ outd, int F)
{
    const int i = blockIdx.x;
    const int t = threadIdx.x;
    float ps = 0.f, pd = 0.f;
    for (int f = t; f < F; f += 256) {
        float v = x[(long)i * F + f];
        ps += v * avs[f];
        pd += v * avd[f];
    }
#pragma unroll
    for (int off = 32; off; off >>= 1) {
        ps += __shfl_down(ps, off);
        pd += __shfl_down(pd, off);
    }
    __shared__ float ls[4], ld[4];
    int lane = t & 63, w = t >> 6;
    if (lane == 0) { ls[w] = ps; ld[w] = pd; }
    __syncthreads();
    if (t == 0) {
        outs[i] = ls[0] + ls[1] + ls[2] + ls[3];
        outd[i] = ld[0] + ld[1] + ld[2] + ld[3];
    }
}

__device__ __forceinline__ float lrelu(float v) {
    return v > 0.f ? v : NEG_SLOPE * v;
}

// ---------------------------- CSR build (by dst) ----------------------------
// edge id t < E: real edge (src[t], dst[t]); t >= E: self loop (t-E, t-E)
__global__ __launch_bounds__(256) void hist_kernel(
    const int* __restrict__ dst, int* __restrict__ cnt, int E, int n)
{
    int t = blockIdx.x * 256 + threadIdx.x;
    if (t >= E + n) return;
    int d = t < E ? dst[t] : (t - E);
    atomicAdd(&cnt[d], 1);
}

#define SCAN_T 1024
__global__ __launch_bounds__(SCAN_T) void scan_kernel(
    const int* __restrict__ cnt, int* __restrict__ off,
    int* __restrict__ cursor, int n)
{
    __shared__ int sums[SCAN_T];
    int t = threadIdx.x;
    int chunk = (n + SCAN_T - 1) / SCAN_T;
    int lo = t * chunk, hi = min(lo + chunk, n);
    int s = 0;
    for (int i = lo; i < hi; ++i) s += cnt[i];
    sums[t] = s;
    __syncthreads();
    for (int d = 1; d < SCAN_T; d <<= 1) {
        int v = (t >= d) ? sums[t - d] : 0;
        __syncthreads();
        sums[t] += v;
        __syncthreads();
    }
    int run = sums[t] - s;  // exclusive prefix of this thread's chunk
    for (int i = lo; i < hi; ++i) {
        off[i] = run;
        cursor[i] = run;
        run += cnt[i];
    }
    if (t == SCAN_T - 1) off[n] = sums[SCAN_T - 1];
}

__global__ __launch_bounds__(256) void scatter_kernel(
    const int* __restrict__ src, const int* __restrict__ dst,
    int* __restrict__ cursor, int* __restrict__ ebuf, int E, int n)
{
    int t = blockIdx.x * 256 + threadIdx.x;
    if (t >= E + n) return;
    int s = t < E ? src[t] : (t - E);
    int d = t < E ? dst[t] : (t - E);
    int pos = atomicAdd(&cursor[d], 1);
    ebuf[pos] = s;
}

// ----------------- per-dst softmax over incoming edges (one wave/dst) -------
__global__ __launch_bounds__(256) void attn_csr_kernel(
    const int* __restrict__ off, const int* __restrict__ ebuf,
    const float* __restrict__ as_, const float* __restrict__ ad_,
    float* __restrict__ alpha, int n)
{
    int d = blockIdx.x * 4 + (threadIdx.x >> 6);
    int lane = threadIdx.x & 63;
    if (d >= n) return;
    int lo = off[d], hi = off[d + 1];
    float adv = ad_[d];
    float m = -INFINITY;
    for (int p = lo + lane; p < hi; p += 64)
        m = fmaxf(m, lrelu(as_[ebuf[p]] + adv));
#pragma unroll
    for (int o = 32; o; o >>= 1) m = fmaxf(m, __shfl_xor(m, o));
    float sum = 0.f;
    for (int p = lo + lane; p < hi; p += 64) {
        float pex = expf(lrelu(as_[ebuf[p]] + adv) - m);
        alpha[p] = pex;
        sum += pex;
    }
#pragma unroll
    for (int o = 32; o; o >>= 1) sum += __shfl_xor(sum, o);
    float inv = 1.f / sum;
    for (int p = lo + lane; p < hi; p += 64) alpha[p] *= inv;
}

// --------- gather-aggregate: out[d] = relu(sum_e alpha_e * x[src_e] + bias) --
// One block per dst. VEC=1: F=256, thread t owns feature t.
// VEC=4: F=1024, thread t owns features [4t,4t+4).
template<int VEC>
__global__ __launch_bounds__(256) void agg_csr_kernel(
    const int* __restrict__ off, const int* __restrict__ ebuf,
    const float* __restrict__ alpha, const float* __restrict__ x,
    const float* __restrict__ bias, float* __restrict__ out)
{
    int d = blockIdx.x;
    int t = threadIdx.x;
    int lo = off[d], hi = off[d + 1];
    if (VEC == 1) {
        float acc = 0.f;
        for (int p = lo; p < hi; ++p) {
            int s = ebuf[p];
            float a = alpha[p];
            acc = fmaf(a, x[(long)s * 256 + t], acc);
        }
        out[(long)d * 256 + t] = fmaxf(acc + bias[t], 0.f);
    } else {
        float4 acc = {0.f, 0.f, 0.f, 0.f};
        for (int p = lo; p < hi; ++p) {
            int s = ebuf[p];
            float a = alpha[p];
            float4 v = *(const float4*)(x + (long)s * 1024 + t * 4);
            acc.x = fmaf(a, v.x, acc.x);
            acc.y = fmaf(a, v.y, acc.y);
            acc.z = fmaf(a, v.z, acc.z);
            acc.w = fmaf(a, v.w, acc.w);
        }
        float4 b4 = *(const float4*)(bias + t * 4);
        float4 r;
        r.x = fmaxf(acc.x + b4.x, 0.f);
        r.y = fmaxf(acc.y + b4.y, 0.f);
        r.z = fmaxf(acc.z + b4.z, 0.f);
        r.w = fmaxf(acc.w + b4.w, 0.f);
        *(float4*)(out + (long)d * 1024 + t * 4) = r;
    }
}

// comb[i] = concat(dfin[didx[i]], cfin[cidx[i]])  (256 + 256)
__global__ __launch_bounds__(256) void gather_concat_kernel(
    const float* __restrict__ dfin, const float* __restrict__ cfin,
    const int* __restrict__ didx, const int* __restrict__ cidx,
    float* __restrict__ comb)
{
    int i = blockIdx.x;
    int t = threadIdx.x;
    int ds = didx[i], cs = cidx[i];
    comb[(long)i * 512 + t] = dfin[(long)ds * 256 + t];
    comb[(long)i * 512 + 256 + t] = cfin[(long)cs * 256 + t];
}

// out[i] = h[i] . w + b[0]   (one wave per row, F=512)
__global__ __launch_bounds__(256) void head_final_kernel(
    const float* __restrict__ h, const float* __restrict__ w,
    const float* __restrict__ b, float* __restrict__ out, int M)
{
    int gw = blockIdx.x * 4 + (threadIdx.x >> 6);
    int lane = threadIdx.x & 63;
    if (gw >= M) return;
    const float* row = h + (long)gw * 512;
    float s = 0.f;
#pragma unroll
    for (int f = lane; f < 512; f += 64) s += row[f] * w[f];
#pragma unroll
    for (int off = 32; off; off >>= 1) s += __shfl_down(s, off);
    if (lane == 0) out[gw] = s + b[0];
}

// ------------------------------ orchestration -------------------------------
static inline dim3 gemm_grid(int M, int N) { return dim3(N / 64, (M + 63) / 64); }

extern "C" void kernel_launch(void* const* d_in, const int* in_sizes, int n_in,
                              void* d_out, int out_size, void* d_ws, size_t ws_size,
                              hipStream_t stream)
{
    const float* drug_x = (const float*)d_in[0];
    const float* cell_x = (const float*)d_in[1];
    const int* d_ei = (const int*)d_in[2];
    const int* c_ei = (const int*)d_in[3];
    const int* d_idx = (const int*)d_in[4];
    const int* c_idx = (const int*)d_in[5];
    const float* dW1 = (const float*)d_in[6];
    const float* db1 = (const float*)d_in[7];
    const float* cW1 = (const float*)d_in[8];
    const float* cb1 = (const float*)d_in[9];
    const float* cW2 = (const float*)d_in[10];
    const float* cb2 = (const float*)d_in[11];
    const float* gdW = (const float*)d_in[12];
    const float* gdas = (const float*)d_in[13];
    const float* gdad = (const float*)d_in[14];
    const float* gdb = (const float*)d_in[15];
    const float* g1W = (const float*)d_in[16];
    const float* g1as = (const float*)d_in[17];
    const float* g1ad = (const float*)d_in[18];
    const float* g1b = (const float*)d_in[19];
    const float* g2W = (const float*)d_in[20];
    const float* g2as = (const float*)d_in[21];
    const float* g2ad = (const float*)d_in[22];
    const float* g2b = (const float*)d_in[23];
    const float* rW1 = (const float*)d_in[24];
    const float* rb1 = (const float*)d_in[25];
    const float* rW2 = (const float*)d_in[26];
    const float* rb2 = (const float*)d_in[27];
    const float* rW3 = (const float*)d_in[28];
    const float* rb3 = (const float*)d_in[29];

    const int ND = in_sizes[0] / 128;     // 50000
    const int NC = in_sizes[1] / 735;     // 10000
    const int ED = in_sizes[2] / 2;       // 800000
    const int EC = in_sizes[3] / 2;       // 160000
    const int NB = in_sizes[4];           // 16384

    const int* d_src = d_ei;
    const int* d_dst = d_ei + ED;
    const int* c_src = c_ei;
    const int* c_dst = c_ei + EC;

    const size_t MB = 1ull << 20;
    char* ws = (char*)d_ws;
    // Arena (all offsets absolute, total <= 156 MB):
    //   A = [0, 52MB)   B = [52, 104MB)   C = [104, 156MB)
    float* A = (float*)ws;
    float* Bb = (float*)(ws + 52 * MB);
    float* Cc = (float*)(ws + 104 * MB);

    // ======================= drug path =======================
    // d0 = relu(drug_x @ dW1 + db1) -> A [ND,256] (51.2MB)
    gemm_bias_act<1><<<gemm_grid(ND, 256), 256, 0, stream>>>(drug_x, dW1, db1, A, ND, 128, 256);
    // xd = d0 @ gdW -> B [ND,256]
    gemm_bias_act<0><<<gemm_grid(ND, 256), 256, 0, stream>>>(A, gdW, nullptr, Bb, ND, 256, 256);
    // d0 (A) dead from here; reuse A for drug CSR scratch.
    int*   doff   = (int*)(ws + 0 * MB);    // ND+1 ints
    int*   dcur   = (int*)(ws + 1 * MB);
    int*   dcnt   = (int*)(ws + 2 * MB);
    int*   debuf  = (int*)(ws + 3 * MB);    // ED+ND ints (3.4MB)
    float* dalpha = (float*)(ws + 7 * MB);  // ED+ND floats (3.4MB)
    float* das    = (float*)(ws + 11 * MB);
    float* dad    = (float*)(ws + 12 * MB);

    att_scalars<<<ND, 256, 0, stream>>>(Bb, gdas, gdad, das, dad, 256);
    hipMemsetAsync(dcnt, 0, (size_t)ND * 4, stream);
    {
        int tot = ED + ND;
        hist_kernel<<<(tot + 255) / 256, 256, 0, stream>>>(d_dst, dcnt, ED, ND);
        scan_kernel<<<1, SCAN_T, 0, stream>>>(dcnt, doff, dcur, ND);
        scatter_kernel<<<(tot + 255) / 256, 256, 0, stream>>>(d_src, d_dst, dcur, debuf, ED, ND);
        attn_csr_kernel<<<(ND + 3) / 4, 256, 0, stream>>>(doff, debuf, das, dad, dalpha, ND);
        // d_final = relu(agg + gdb) -> C [ND,256]
        agg_csr_kernel<1><<<ND, 256, 0, stream>>>(doff, debuf, dalpha, Bb, gdb, Cc);
    }

    // ======================= cell path =======================
    float* c0 = A;                           // [NC,1024] 40MB @ [0,40)
    float* c1 = (float*)(ws + 42 * MB);      // [NC,256] 10MB @ [42,52)
    float* xc1 = Bb;                         // [NC,1024] 40MB @ [52,92)
    // c0 = relu(cell_x @ cW1 + cb1)
    gemm_bias_act<1><<<gemm_grid(NC, 1024), 256, 0, stream>>>(cell_x, cW1, cb1, c0, NC, 735, 1024);
    // c1 = relu(c0 @ cW2 + cb2)
    gemm_bias_act<1><<<gemm_grid(NC, 256), 256, 0, stream>>>(c0, cW2, cb2, c1, NC, 1024, 256);
    // xc1 = c1 @ g1W
    gemm_bias_act<0><<<gemm_grid(NC, 1024), 256, 0, stream>>>(c1, g1W, nullptr, xc1, NC, 256, 1024);
    // c0 dead; reuse A-front for cell CSR (shared by both cell GAT layers).
    int*   coff   = (int*)(ws + 0 * MB);
    int*   ccur   = (int*)(ws + 1 * MB);
    int*   ccnt   = (int*)(ws + 2 * MB);
    int*   cebuf  = (int*)(ws + 3 * MB);     // EC+NC ints (0.68MB)
    float* calpha = (float*)(ws + 4 * MB);
    float* cas    = (float*)(ws + 5 * MB);
    float* cad    = (float*)(ws + 6 * MB);
    float* c2     = (float*)(ws + 8 * MB);   // [NC,1024] 40MB @ [8,48)
    float* xc2    = Bb;                      // [NC,256] 10MB @ [52,62)
    float* cfin   = (float*)(ws + 64 * MB);  // [NC,256] 10MB @ [64,74)

    att_scalars<<<NC, 256, 0, stream>>>(xc1, g1as, g1ad, cas, cad, 1024);
    hipMemsetAsync(ccnt, 0, (size_t)NC * 4, stream);
    {
        int tot = EC + NC;
        hist_kernel<<<(tot + 255) / 256, 256, 0, stream>>>(c_dst, ccnt, EC, NC);
        scan_kernel<<<1, SCAN_T, 0, stream>>>(ccnt, coff, ccur, NC);
        scatter_kernel<<<(tot + 255) / 256, 256, 0, stream>>>(c_src, c_dst, ccur, cebuf, EC, NC);
        attn_csr_kernel<<<(NC + 3) / 4, 256, 0, stream>>>(coff, cebuf, cas, cad, calpha, NC);
        // c2 = relu(agg + g1b)
        agg_csr_kernel<4><<<NC, 256, 0, stream>>>(coff, cebuf, calpha, xc1, g1b, c2);
    }
    // xc2 = c2 @ g2W
    gemm_bias_act<0><<<gemm_grid(NC, 256), 256, 0, stream>>>(c2, g2W, nullptr, xc2, NC, 1024, 256);
    att_scalars<<<NC, 256, 0, stream>>>(xc2, g2as, g2ad, cas, cad, 256);
    {
        // CSR structure (coff/cebuf) reused — same graph.
        attn_csr_kernel<<<(NC + 3) / 4, 256, 0, stream>>>(coff, cebuf, cas, cad, calpha, NC);
        // c_final = relu(agg + g2b)
        agg_csr_kernel<1><<<NC, 256, 0, stream>>>(coff, cebuf, calpha, xc2, g2b, cfin);
    }

    // ======================= head =======================
    float* comb = A;                        // [NB,512] 32MB @ [0,32)
    float* h1 = Cc;                         // [NB,512] 32MB @ [104,136)  (d_final dead after gather)
    float* h2 = A;                          // [NB,512] 32MB @ [0,32)     (comb dead after h1)
    gather_concat_kernel<<<NB, 256, 0, stream>>>(Cc, cfin, d_idx, c_idx, comb);
    gemm_bias_act<2><<<gemm_grid(NB, 512), 256, 0, stream>>>(comb, rW1, rb1, h1, NB, 512, 512);
    gemm_bias_act<2><<<gemm_grid(NB, 512), 256, 0, stream>>>(h1, rW2, rb2, h2, NB, 512, 512);
    head_final_kernel<<<(NB + 3) / 4, 256, 0, stream>>>(h2, rW3, rb3, (float*)d_out, NB);
}

// Round 3
// 1389.341 us; speedup vs baseline: 5.3548x; 1.5126x over previous
//
#include <hip/hip_runtime.h>
#include <math.h>

#define NEG_SLOPE 0.2f

typedef __attribute__((ext_vector_type(8))) short short8;
typedef __attribute__((ext_vector_type(4))) float floatx4;

// ---------------- fp32 <-> bf16 split helpers (RNE) ----------------
__device__ __forceinline__ unsigned short f2bf(float f) {
    unsigned u = __float_as_uint(f);
    u += 0x7fffu + ((u >> 16) & 1u);
    return (unsigned short)(u >> 16);
}
__device__ __forceinline__ float bf2f(unsigned short h) {
    return __uint_as_float((unsigned)h << 16);
}

// ---------------- weight pre-pass: W[K][N] fp32 -> Wt_hi/lo[N][Kp] bf16 -----
__global__ __launch_bounds__(256) void split_transpose(
    const float* __restrict__ W, unsigned short* __restrict__ Th,
    unsigned short* __restrict__ Tl, int K, int N, int Kp)
{
    __shared__ float t[32][33];
    int k0 = blockIdx.y * 32, n0 = blockIdx.x * 32;
    int c = threadIdx.x & 31, r = threadIdx.x >> 5;  // r in 0..7
    for (int rr = r; rr < 32; rr += 8) {
        int k = k0 + rr, n = n0 + c;
        t[rr][c] = (k < K && n < N) ? W[(long)k * N + n] : 0.f;
    }
    __syncthreads();
    for (int rr = r; rr < 32; rr += 8) {
        int n = n0 + rr, k = k0 + c;
        if (n < N && k < Kp) {
            float v = t[c][rr];
            unsigned short h = f2bf(v);
            Th[(long)n * Kp + k] = h;
            Tl[(long)n * Kp + k] = f2bf(v - bf2f(h));
        }
    }
}

// ---------------- GEMM via split-bf16 MFMA: C = act(A @ B + bias) -----------
// A fp32 [M][K] (split on the fly); B pre-split bf16 [N][Kp] hi/lo planes.
// 128x128 block, BK=32, 4 waves each owning a 64x64 quadrant (4x4 MFMA tiles).
// 3 MFMAs per tile pair: AhBh + AlBh + AhBl (rel err ~2^-15.7).
template<int ACT>  // 0=none, 1=relu, 2=elu
__global__ __launch_bounds__(256, 2) void gemm_mfma(
    const float* __restrict__ A, const unsigned short* __restrict__ Bh_g,
    const unsigned short* __restrict__ Bl_g, const float* __restrict__ bias,
    float* __restrict__ C, int M, int K, int N, int Kp)
{
    __shared__ unsigned short Ah[128][40];
    __shared__ unsigned short Al[128][40];
    __shared__ unsigned short Bh[128][40];
    __shared__ unsigned short Bl[128][40];
    const int tid = threadIdx.x;
    const int wave = tid >> 6, lane = tid & 63;
    const int lm = lane & 15, lq = lane >> 4;
    const int wm = (wave & 1) << 6, wn = (wave >> 1) << 6;
    const int m0 = blockIdx.y * 128, n0 = blockIdx.x * 128;
    floatx4 acc[4][4];
    floatx4 zero = {0.f, 0.f, 0.f, 0.f};
#pragma unroll
    for (int i = 0; i < 4; ++i)
#pragma unroll
        for (int j = 0; j < 4; ++j) acc[i][j] = zero;

    const bool k4 = (K & 3) == 0;
    const int brow = tid >> 1, bhalf = tid & 1;

    for (int k0 = 0; k0 < K; k0 += 32) {
        // ---- stage A tile [128m][32k]: fp32 load, split to hi/lo bf16 ----
#pragma unroll
        for (int it = 0; it < 4; ++it) {
            int slot = tid + it * 256;
            int row = slot >> 3, kq = slot & 7;
            int gm = m0 + row, kb = k0 + kq * 4;
            float v0 = 0.f, v1 = 0.f, v2 = 0.f, v3 = 0.f;
            if (gm < M) {
                if (k4 && kb + 4 <= K) {
                    float4 t = *(const float4*)(A + (long)gm * K + kb);
                    v0 = t.x; v1 = t.y; v2 = t.z; v3 = t.w;
                } else {
                    if (kb + 0 < K) v0 = A[(long)gm * K + kb + 0];
                    if (kb + 1 < K) v1 = A[(long)gm * K + kb + 1];
                    if (kb + 2 < K) v2 = A[(long)gm * K + kb + 2];
                    if (kb + 3 < K) v3 = A[(long)gm * K + kb + 3];
                }
            }
            unsigned short h0 = f2bf(v0), h1 = f2bf(v1), h2 = f2bf(v2), h3 = f2bf(v3);
            unsigned short l0 = f2bf(v0 - bf2f(h0)), l1 = f2bf(v1 - bf2f(h1));
            unsigned short l2 = f2bf(v2 - bf2f(h2)), l3 = f2bf(v3 - bf2f(h3));
            uint2 ph = {(unsigned)h0 | ((unsigned)h1 << 16), (unsigned)h2 | ((unsigned)h3 << 16)};
            uint2 pl = {(unsigned)l0 | ((unsigned)l1 << 16), (unsigned)l2 | ((unsigned)l3 << 16)};
            *(uint2*)&Ah[row][kq * 4] = ph;
            *(uint2*)&Al[row][kq * 4] = pl;
        }
        // ---- stage B tile [128n][32k]: pre-split, coalesced 16B loads ----
        {
            long bb = (long)(n0 + brow) * Kp + k0 + bhalf * 16;
            uint4 x0 = *(const uint4*)(Bh_g + bb);
            uint4 x1 = *(const uint4*)(Bh_g + bb + 8);
            *(uint4*)&Bh[brow][bhalf * 16] = x0;
            *(uint4*)&Bh[brow][bhalf * 16 + 8] = x1;
            uint4 y0 = *(const uint4*)(Bl_g + bb);
            uint4 y1 = *(const uint4*)(Bl_g + bb + 8);
            *(uint4*)&Bl[brow][bhalf * 16] = y0;
            *(uint4*)&Bl[brow][bhalf * 16 + 8] = y1;
        }
        __syncthreads();
        short8 fah[4], fal[4], fbh[4], fbl[4];
#pragma unroll
        for (int i = 0; i < 4; ++i) {
            fah[i] = *(const short8*)&Ah[wm + i * 16 + lm][lq * 8];
            fal[i] = *(const short8*)&Al[wm + i * 16 + lm][lq * 8];
        }
#pragma unroll
        for (int j = 0; j < 4; ++j) {
            fbh[j] = *(const short8*)&Bh[wn + j * 16 + lm][lq * 8];
            fbl[j] = *(const short8*)&Bl[wn + j * 16 + lm][lq * 8];
        }
#pragma unroll
        for (int i = 0; i < 4; ++i)
#pragma unroll
            for (int j = 0; j < 4; ++j) {
                acc[i][j] = __builtin_amdgcn_mfma_f32_16x16x32_bf16(fah[i], fbh[j], acc[i][j], 0, 0, 0);
                acc[i][j] = __builtin_amdgcn_mfma_f32_16x16x32_bf16(fal[i], fbh[j], acc[i][j], 0, 0, 0);
                acc[i][j] = __builtin_amdgcn_mfma_f32_16x16x32_bf16(fah[i], fbl[j], acc[i][j], 0, 0, 0);
            }
        __syncthreads();
    }
    // ---- epilogue: C/D layout col=lane&15, row=quad*4+reg (m89-verified) ----
#pragma unroll
    for (int j = 0; j < 4; ++j) {
        int gn = n0 + wn + j * 16 + lm;
        float bv = bias ? bias[gn] : 0.f;
#pragma unroll
        for (int i = 0; i < 4; ++i) {
#pragma unroll
            for (int r = 0; r < 4; ++r) {
                int gm = m0 + wm + i * 16 + lq * 4 + r;
                if (gm < M) {
                    float v = acc[i][j][r] + bv;
                    if (ACT == 1) v = fmaxf(v, 0.f);
                    if (ACT == 2) v = v > 0.f ? v : expm1f(v);
                    C[(long)gm * N + gn] = v;
                }
            }
        }
    }
}

// ---------------- GAT attention scalars ----------------
__global__ __launch_bounds__(256) void att_scalars(
    const float* __restrict__ x, const float* __restrict__ avs,
    const float* __restrict__ avd, float* __restrict__ outs,
    float* __restrict__ outd, int F)
{
    const int i = blockIdx.x;
    const int t = threadIdx.x;
    float ps = 0.f, pd = 0.f;
    for (int f = t; f < F; f += 256) {
        float v = x[(long)i * F + f];
        ps += v * avs[f];
        pd += v * avd[f];
    }
#pragma unroll
    for (int off = 32; off; off >>= 1) {
        ps += __shfl_down(ps, off);
        pd += __shfl_down(pd, off);
    }
    __shared__ float ls[4], ld[4];
    int lane = t & 63, w = t >> 6;
    if (lane == 0) { ls[w] = ps; ld[w] = pd; }
    __syncthreads();
    if (t == 0) {
        outs[i] = ls[0] + ls[1] + ls[2] + ls[3];
        outd[i] = ld[0] + ld[1] + ld[2] + ld[3];
    }
}

__device__ __forceinline__ float lrelu(float v) {
    return v > 0.f ? v : NEG_SLOPE * v;
}

// ---------------------------- CSR build (by dst) ----------------------------
__global__ __launch_bounds__(256) void hist_kernel(
    const int* __restrict__ dst, int* __restrict__ cnt, int E, int n)
{
    int t = blockIdx.x * 256 + threadIdx.x;
    if (t >= E + n) return;
    int d = t < E ? dst[t] : (t - E);
    atomicAdd(&cnt[d], 1);
}

#define SCAN_T 1024
__global__ __launch_bounds__(SCAN_T) void scan_kernel(
    const int* __restrict__ cnt, int* __restrict__ off,
    int* __restrict__ cursor, int n)
{
    __shared__ int sums[SCAN_T];
    int t = threadIdx.x;
    int chunk = (n + SCAN_T - 1) / SCAN_T;
    int lo = t * chunk, hi = min(lo + chunk, n);
    int s = 0;
    for (int i = lo; i < hi; ++i) s += cnt[i];
    sums[t] = s;
    __syncthreads();
    for (int d = 1; d < SCAN_T; d <<= 1) {
        int v = (t >= d) ? sums[t - d] : 0;
        __syncthreads();
        sums[t] += v;
        __syncthreads();
    }
    int run = sums[t] - s;
    for (int i = lo; i < hi; ++i) {
        off[i] = run;
        cursor[i] = run;
        run += cnt[i];
    }
    if (t == SCAN_T - 1) off[n] = sums[SCAN_T - 1];
}

__global__ __launch_bounds__(256) void scatter_kernel(
    const int* __restrict__ src, const int* __restrict__ dst,
    int* __restrict__ cursor, int* __restrict__ ebuf, int E, int n)
{
    int t = blockIdx.x * 256 + threadIdx.x;
    if (t >= E + n) return;
    int s = t < E ? src[t] : (t - E);
    int d = t < E ? dst[t] : (t - E);
    int pos = atomicAdd(&cursor[d], 1);
    ebuf[pos] = s;
}

// ----------------- per-dst softmax over incoming edges (one wave/dst) -------
__global__ __launch_bounds__(256) void attn_csr_kernel(
    const int* __restrict__ off, const int* __restrict__ ebuf,
    const float* __restrict__ as_, const float* __restrict__ ad_,
    float* __restrict__ alpha, int n)
{
    int d = blockIdx.x * 4 + (threadIdx.x >> 6);
    int lane = threadIdx.x & 63;
    if (d >= n) return;
    int lo = off[d], hi = off[d + 1];
    float adv = ad_[d];
    float m = -INFINITY;
    for (int p = lo + lane; p < hi; p += 64)
        m = fmaxf(m, lrelu(as_[ebuf[p]] + adv));
#pragma unroll
    for (int o = 32; o; o >>= 1) m = fmaxf(m, __shfl_xor(m, o));
    float sum = 0.f;
    for (int p = lo + lane; p < hi; p += 64) {
        float pex = expf(lrelu(as_[ebuf[p]] + adv) - m);
        alpha[p] = pex;
        sum += pex;
    }
#pragma unroll
    for (int o = 32; o; o >>= 1) sum += __shfl_xor(sum, o);
    float inv = 1.f / sum;
    for (int p = lo + lane; p < hi; p += 64) alpha[p] *= inv;
}

// --------- gather-aggregate: out[d] = relu(sum_e alpha_e * x[src_e] + bias) --
template<int VEC>
__global__ __launch_bounds__(256) void agg_csr_kernel(
    const int* __restrict__ off, const int* __restrict__ ebuf,
    const float* __restrict__ alpha, const float* __restrict__ x,
    const float* __restrict__ bias, float* __restrict__ out)
{
    int d = blockIdx.x;
    int t = threadIdx.x;
    int lo = off[d], hi = off[d + 1];
    if (VEC == 1) {
        float acc = 0.f;
        for (int p = lo; p < hi; ++p) {
            int s = ebuf[p];
            float a = alpha[p];
            acc = fmaf(a, x[(long)s * 256 + t], acc);
        }
        out[(long)d * 256 + t] = fmaxf(acc + bias[t], 0.f);
    } else {
        float4 acc = {0.f, 0.f, 0.f, 0.f};
        for (int p = lo; p < hi; ++p) {
            int s = ebuf[p];
            float a = alpha[p];
            float4 v = *(const float4*)(x + (long)s * 1024 + t * 4);
            acc.x = fmaf(a, v.x, acc.x);
            acc.y = fmaf(a, v.y, acc.y);
            acc.z = fmaf(a, v.z, acc.z);
            acc.w = fmaf(a, v.w, acc.w);
        }
        float4 b4 = *(const float4*)(bias + t * 4);
        float4 r;
        r.x = fmaxf(acc.x + b4.x, 0.f);
        r.y = fmaxf(acc.y + b4.y, 0.f);
        r.z = fmaxf(acc.z + b4.z, 0.f);
        r.w = fmaxf(acc.w + b4.w, 0.f);
        *(float4*)(out + (long)d * 1024 + t * 4) = r;
    }
}

// comb[i] = concat(dfin[didx[i]], cfin[cidx[i]])
__global__ __launch_bounds__(256) void gather_concat_kernel(
    const float* __restrict__ dfin, const float* __restrict__ cfin,
    const int* __restrict__ didx, const int* __restrict__ cidx,
    float* __restrict__ comb)
{
    int i = blockIdx.x;
    int t = threadIdx.x;
    int ds = didx[i], cs = cidx[i];
    comb[(long)i * 512 + t] = dfin[(long)ds * 256 + t];
    comb[(long)i * 512 + 256 + t] = cfin[(long)cs * 256 + t];
}

// out[i] = h[i] . w + b[0]
__global__ __launch_bounds__(256) void head_final_kernel(
    const float* __restrict__ h, const float* __restrict__ w,
    const float* __restrict__ b, float* __restrict__ out, int M)
{
    int gw = blockIdx.x * 4 + (threadIdx.x >> 6);
    int lane = threadIdx.x & 63;
    if (gw >= M) return;
    const float* row = h + (long)gw * 512;
    float s = 0.f;
#pragma unroll
    for (int f = lane; f < 512; f += 64) s += row[f] * w[f];
#pragma unroll
    for (int off = 32; off; off >>= 1) s += __shfl_down(s, off);
    if (lane == 0) out[gw] = s + b[0];
}

// ------------------------------ orchestration -------------------------------
static inline dim3 mfma_grid(int M, int N) { return dim3(N / 128, (M + 127) / 128); }

extern "C" void kernel_launch(void* const* d_in, const int* in_sizes, int n_in,
                              void* d_out, int out_size, void* d_ws, size_t ws_size,
                              hipStream_t stream)
{
    const float* drug_x = (const float*)d_in[0];
    const float* cell_x = (const float*)d_in[1];
    const int* d_ei = (const int*)d_in[2];
    const int* c_ei = (const int*)d_in[3];
    const int* d_idx = (const int*)d_in[4];
    const int* c_idx = (const int*)d_in[5];
    const float* dW1 = (const float*)d_in[6];
    const float* db1 = (const float*)d_in[7];
    const float* cW1 = (const float*)d_in[8];
    const float* cb1 = (const float*)d_in[9];
    const float* cW2 = (const float*)d_in[10];
    const float* cb2 = (const float*)d_in[11];
    const float* gdW = (const float*)d_in[12];
    const float* gdas = (const float*)d_in[13];
    const float* gdad = (const float*)d_in[14];
    const float* gdb = (const float*)d_in[15];
    const float* g1W = (const float*)d_in[16];
    const float* g1as = (const float*)d_in[17];
    const float* g1ad = (const float*)d_in[18];
    const float* g1b = (const float*)d_in[19];
    const float* g2W = (const float*)d_in[20];
    const float* g2as = (const float*)d_in[21];
    const float* g2ad = (const float*)d_in[22];
    const float* g2b = (const float*)d_in[23];
    const float* rW1 = (const float*)d_in[24];
    const float* rb1 = (const float*)d_in[25];
    const float* rW2 = (const float*)d_in[26];
    const float* rb2 = (const float*)d_in[27];
    const float* rW3 = (const float*)d_in[28];
    const float* rb3 = (const float*)d_in[29];

    const int ND = in_sizes[0] / 128;     // 50000
    const int NC = in_sizes[1] / 735;     // 10000
    const int ED = in_sizes[2] / 2;       // 800000
    const int EC = in_sizes[3] / 2;       // 160000
    const int NB = in_sizes[4];           // 16384

    const int* d_src = d_ei;
    const int* d_dst = d_ei + ED;
    const int* c_src = c_ei;
    const int* c_dst = c_ei + EC;

    const size_t MB = 1ull << 20;
    const size_t KB = 1024;
    char* ws = (char*)d_ws;

    // ---- weight split region [0, 9MB) ----
    size_t wo = 0;
    auto walloc = [&](size_t elems) -> unsigned short* {
        unsigned short* p = (unsigned short*)(ws + wo);
        wo += ((elems * 2 + 255) & ~(size_t)255);
        return p;
    };
    unsigned short* dW1h = walloc(256 * 128);  unsigned short* dW1l = walloc(256 * 128);
    unsigned short* cW1h = walloc(1024 * 736); unsigned short* cW1l = walloc(1024 * 736);
    unsigned short* cW2h = walloc(256 * 1024); unsigned short* cW2l = walloc(256 * 1024);
    unsigned short* gdWh = walloc(256 * 256);  unsigned short* gdWl = walloc(256 * 256);
    unsigned short* g1Wh = walloc(1024 * 256); unsigned short* g1Wl = walloc(1024 * 256);
    unsigned short* g2Wh = walloc(256 * 1024); unsigned short* g2Wl = walloc(256 * 1024);
    unsigned short* rW1h = walloc(512 * 512);  unsigned short* rW1l = walloc(512 * 512);
    unsigned short* rW2h = walloc(512 * 512);  unsigned short* rW2l = walloc(512 * 512);

    // ---- activation / scratch arena (liveness-checked) ----
    float* dbuf  = (float*)(ws + 9 * MB);              // d0, then d_final [ND,256] -> [9,60.2)
    float* xd    = (float*)(ws + 61 * MB);             // [61,112.2)
    float* das   = (float*)(ws + 113 * MB);            // drug scratch [113,125)
    float* dad   = (float*)(ws + 113 * MB + 512 * KB);
    int*   doff  = (int*)(ws + 114 * MB);
    int*   dcur  = (int*)(ws + 114 * MB + 512 * KB);
    int*   dcnt  = (int*)(ws + 115 * MB);
    int*   debuf = (int*)(ws + 115 * MB + 512 * KB);   // (ED+ND)*4 = 3.24MB
    float* dalpha= (float*)(ws + 119 * MB);            // 3.24MB -> ends 122.3
    float* c0b   = (float*)(ws + 61 * MB);             // [61,101)   (xd dead)
    float* c1b   = (float*)(ws + 101 * MB);            // [101,111)
    float* xc1   = (float*)(ws + 113 * MB);            // [113,153)  (drug scratch dead)
    float* cas   = (float*)(ws + 61 * MB);             // cell scratch [61,63) (c0 dead)
    float* cad   = (float*)(ws + 61 * MB + 64 * KB);
    int*   coff  = (int*)(ws + 61 * MB + 128 * KB);
    int*   ccur  = (int*)(ws + 61 * MB + 192 * KB);
    int*   ccnt  = (int*)(ws + 61 * MB + 256 * KB);
    int*   cebuf = (int*)(ws + 61 * MB + 320 * KB);    // 680KB
    float* calpha= (float*)(ws + 62 * MB + 256 * KB);  // 680KB -> ends ~62.93
    float* c2b   = (float*)(ws + 63 * MB);             // [63,103)
    float* xc2   = (float*)(ws + 103 * MB);            // [103,113)
    float* cfin  = (float*)(ws + 113 * MB);            // [113,123)  (xc1 dead)
    float* comb  = (float*)(ws + 123 * MB);            // [123,155)
    float* h1b   = (float*)(ws + 63 * MB);             // [63,95)    (c2 dead)
    float* h2b   = (float*)(ws + 123 * MB);            // [123,155)  (comb dead)

    // ================= weight pre-split (once per launch, ~12MB) =============
    split_transpose<<<dim3(256 / 32, 128 / 32), 256, 0, stream>>>(dW1, dW1h, dW1l, 128, 256, 128);
    split_transpose<<<dim3(1024 / 32, 736 / 32), 256, 0, stream>>>(cW1, cW1h, cW1l, 735, 1024, 736);
    split_transpose<<<dim3(256 / 32, 1024 / 32), 256, 0, stream>>>(cW2, cW2h, cW2l, 1024, 256, 1024);
    split_transpose<<<dim3(256 / 32, 256 / 32), 256, 0, stream>>>(gdW, gdWh, gdWl, 256, 256, 256);
    split_transpose<<<dim3(1024 / 32, 256 / 32), 256, 0, stream>>>(g1W, g1Wh, g1Wl, 256, 1024, 256);
    split_transpose<<<dim3(256 / 32, 1024 / 32), 256, 0, stream>>>(g2W, g2Wh, g2Wl, 1024, 256, 1024);
    split_transpose<<<dim3(512 / 32, 512 / 32), 256, 0, stream>>>(rW1, rW1h, rW1l, 512, 512, 512);
    split_transpose<<<dim3(512 / 32, 512 / 32), 256, 0, stream>>>(rW2, rW2h, rW2l, 512, 512, 512);

    // ======================= drug path =======================
    gemm_mfma<1><<<mfma_grid(ND, 256), 256, 0, stream>>>(drug_x, dW1h, dW1l, db1, dbuf, ND, 128, 256, 128);
    gemm_mfma<0><<<mfma_grid(ND, 256), 256, 0, stream>>>(dbuf, gdWh, gdWl, nullptr, xd, ND, 256, 256, 256);
    att_scalars<<<ND, 256, 0, stream>>>(xd, gdas, gdad, das, dad, 256);
    hipMemsetAsync(dcnt, 0, (size_t)ND * 4, stream);
    {
        int tot = ED + ND;
        hist_kernel<<<(tot + 255) / 256, 256, 0, stream>>>(d_dst, dcnt, ED, ND);
        scan_kernel<<<1, SCAN_T, 0, stream>>>(dcnt, doff, dcur, ND);
        scatter_kernel<<<(tot + 255) / 256, 256, 0, stream>>>(d_src, d_dst, dcur, debuf, ED, ND);
        attn_csr_kernel<<<(ND + 3) / 4, 256, 0, stream>>>(doff, debuf, das, dad, dalpha, ND);
        agg_csr_kernel<1><<<ND, 256, 0, stream>>>(doff, debuf, dalpha, xd, gdb, dbuf);  // d_final -> dbuf
    }

    // ======================= cell path =======================
    gemm_mfma<1><<<mfma_grid(NC, 1024), 256, 0, stream>>>(cell_x, cW1h, cW1l, cb1, c0b, NC, 735, 1024, 736);
    gemm_mfma<1><<<mfma_grid(NC, 256), 256, 0, stream>>>(c0b, cW2h, cW2l, cb2, c1b, NC, 1024, 256, 1024);
    gemm_mfma<0><<<mfma_grid(NC, 1024), 256, 0, stream>>>(c1b, g1Wh, g1Wl, nullptr, xc1, NC, 256, 1024, 256);
    att_scalars<<<NC, 256, 0, stream>>>(xc1, g1as, g1ad, cas, cad, 1024);
    hipMemsetAsync(ccnt, 0, (size_t)NC * 4, stream);
    {
        int tot = EC + NC;
        hist_kernel<<<(tot + 255) / 256, 256, 0, stream>>>(c_dst, ccnt, EC, NC);
        scan_kernel<<<1, SCAN_T, 0, stream>>>(ccnt, coff, ccur, NC);
        scatter_kernel<<<(tot + 255) / 256, 256, 0, stream>>>(c_src, c_dst, ccur, cebuf, EC, NC);
        attn_csr_kernel<<<(NC + 3) / 4, 256, 0, stream>>>(coff, cebuf, cas, cad, calpha, NC);
        agg_csr_kernel<4><<<NC, 256, 0, stream>>>(coff, cebuf, calpha, xc1, g1b, c2b);  // c2
    }
    gemm_mfma<0><<<mfma_grid(NC, 256), 256, 0, stream>>>(c2b, g2Wh, g2Wl, nullptr, xc2, NC, 1024, 256, 1024);
    att_scalars<<<NC, 256, 0, stream>>>(xc2, g2as, g2ad, cas, cad, 256);
    {
        attn_csr_kernel<<<(NC + 3) / 4, 256, 0, stream>>>(coff, cebuf, cas, cad, calpha, NC);
        agg_csr_kernel<1><<<NC, 256, 0, stream>>>(coff, cebuf, calpha, xc2, g2b, cfin);
    }

    // ======================= head =======================
    gather_concat_kernel<<<NB, 256, 0, stream>>>(dbuf, cfin, d_idx, c_idx, comb);
    gemm_mfma<2><<<mfma_grid(NB, 512), 256, 0, stream>>>(comb, rW1h, rW1l, rb1, h1b, NB, 512, 512, 512);
    gemm_mfma<2><<<mfma_grid(NB, 512), 256, 0, stream>>>(h1b, rW2h, rW2l, rb2, h2b, NB, 512, 512, 512);
    head_final_kernel<<<(NB + 3) / 4, 256, 0, stream>>>(h2b, rW3, rb3, (float*)d_out, NB);
}

// Round 4
// 1240.204 us; speedup vs baseline: 5.9987x; 1.1203x over previous
//
#include <hip/hip_runtime.h>
#include <math.h>

#define NEG_SLOPE 0.2f

typedef __attribute__((ext_vector_type(8))) short short8;
typedef __attribute__((ext_vector_type(4))) float floatx4;

// ---------------- fp32 <-> bf16 split helpers (RNE) ----------------
__device__ __forceinline__ unsigned short f2bf(float f) {
    unsigned u = __float_as_uint(f);
    u += 0x7fffu + ((u >> 16) & 1u);
    return (unsigned short)(u >> 16);
}
__device__ __forceinline__ float bf2f(unsigned short h) {
    return __uint_as_float((unsigned)h << 16);
}

// ---------------- weight pre-pass: W[K][N] fp32 -> Wt_hi/lo[N][Kp] bf16 -----
__global__ __launch_bounds__(256) void split_transpose(
    const float* __restrict__ W, unsigned short* __restrict__ Th,
    unsigned short* __restrict__ Tl, int K, int N, int Kp)
{
    __shared__ float t[32][33];
    int k0 = blockIdx.y * 32, n0 = blockIdx.x * 32;
    int c = threadIdx.x & 31, r = threadIdx.x >> 5;  // r in 0..7
    for (int rr = r; rr < 32; rr += 8) {
        int k = k0 + rr, n = n0 + c;
        t[rr][c] = (k < K && n < N) ? W[(long)k * N + n] : 0.f;
    }
    __syncthreads();
    for (int rr = r; rr < 32; rr += 8) {
        int n = n0 + rr, k = k0 + c;
        if (n < N && k < Kp) {
            float v = t[c][rr];
            unsigned short h = f2bf(v);
            Th[(long)n * Kp + k] = h;
            Tl[(long)n * Kp + k] = f2bf(v - bf2f(h));
        }
    }
}

// ---------------- GEMM via split-bf16 MFMA: C = act(A @ B + bias) -----------
template<int ACT>  // 0=none, 1=relu, 2=elu
__global__ __launch_bounds__(256, 2) void gemm_mfma(
    const float* __restrict__ A, const unsigned short* __restrict__ Bh_g,
    const unsigned short* __restrict__ Bl_g, const float* __restrict__ bias,
    float* __restrict__ C, int M, int K, int N, int Kp)
{
    __shared__ unsigned short Ah[128][40];
    __shared__ unsigned short Al[128][40];
    __shared__ unsigned short Bh[128][40];
    __shared__ unsigned short Bl[128][40];
    const int tid = threadIdx.x;
    const int wave = tid >> 6, lane = tid & 63;
    const int lm = lane & 15, lq = lane >> 4;
    const int wm = (wave & 1) << 6, wn = (wave >> 1) << 6;
    const int m0 = blockIdx.y * 128, n0 = blockIdx.x * 128;
    floatx4 acc[4][4];
    floatx4 zero = {0.f, 0.f, 0.f, 0.f};
#pragma unroll
    for (int i = 0; i < 4; ++i)
#pragma unroll
        for (int j = 0; j < 4; ++j) acc[i][j] = zero;

    const bool k4 = (K & 3) == 0;
    const int brow = tid >> 1, bhalf = tid & 1;

    for (int k0 = 0; k0 < K; k0 += 32) {
        // ---- stage A tile [128m][32k]: fp32 load, split to hi/lo bf16 ----
#pragma unroll
        for (int it = 0; it < 4; ++it) {
            int slot = tid + it * 256;
            int row = slot >> 3, kq = slot & 7;
            int gm = m0 + row, kb = k0 + kq * 4;
            float v0 = 0.f, v1 = 0.f, v2 = 0.f, v3 = 0.f;
            if (gm < M) {
                if (k4 && kb + 4 <= K) {
                    float4 t = *(const float4*)(A + (long)gm * K + kb);
                    v0 = t.x; v1 = t.y; v2 = t.z; v3 = t.w;
                } else {
                    if (kb + 0 < K) v0 = A[(long)gm * K + kb + 0];
                    if (kb + 1 < K) v1 = A[(long)gm * K + kb + 1];
                    if (kb + 2 < K) v2 = A[(long)gm * K + kb + 2];
                    if (kb + 3 < K) v3 = A[(long)gm * K + kb + 3];
                }
            }
            unsigned short h0 = f2bf(v0), h1 = f2bf(v1), h2 = f2bf(v2), h3 = f2bf(v3);
            unsigned short l0 = f2bf(v0 - bf2f(h0)), l1 = f2bf(v1 - bf2f(h1));
            unsigned short l2 = f2bf(v2 - bf2f(h2)), l3 = f2bf(v3 - bf2f(h3));
            uint2 ph = {(unsigned)h0 | ((unsigned)h1 << 16), (unsigned)h2 | ((unsigned)h3 << 16)};
            uint2 pl = {(unsigned)l0 | ((unsigned)l1 << 16), (unsigned)l2 | ((unsigned)l3 << 16)};
            *(uint2*)&Ah[row][kq * 4] = ph;
            *(uint2*)&Al[row][kq * 4] = pl;
        }
        // ---- stage B tile [128n][32k]: pre-split, coalesced 16B loads ----
        {
            long bb = (long)(n0 + brow) * Kp + k0 + bhalf * 16;
            uint4 x0 = *(const uint4*)(Bh_g + bb);
            uint4 x1 = *(const uint4*)(Bh_g + bb + 8);
            *(uint4*)&Bh[brow][bhalf * 16] = x0;
            *(uint4*)&Bh[brow][bhalf * 16 + 8] = x1;
            uint4 y0 = *(const uint4*)(Bl_g + bb);
            uint4 y1 = *(const uint4*)(Bl_g + bb + 8);
            *(uint4*)&Bl[brow][bhalf * 16] = y0;
            *(uint4*)&Bl[brow][bhalf * 16 + 8] = y1;
        }
        __syncthreads();
        short8 fah[4], fal[4], fbh[4], fbl[4];
#pragma unroll
        for (int i = 0; i < 4; ++i) {
            fah[i] = *(const short8*)&Ah[wm + i * 16 + lm][lq * 8];
            fal[i] = *(const short8*)&Al[wm + i * 16 + lm][lq * 8];
        }
#pragma unroll
        for (int j = 0; j < 4; ++j) {
            fbh[j] = *(const short8*)&Bh[wn + j * 16 + lm][lq * 8];
            fbl[j] = *(const short8*)&Bl[wn + j * 16 + lm][lq * 8];
        }
#pragma unroll
        for (int i = 0; i < 4; ++i)
#pragma unroll
            for (int j = 0; j < 4; ++j) {
                acc[i][j] = __builtin_amdgcn_mfma_f32_16x16x32_bf16(fah[i], fbh[j], acc[i][j], 0, 0, 0);
                acc[i][j] = __builtin_amdgcn_mfma_f32_16x16x32_bf16(fal[i], fbh[j], acc[i][j], 0, 0, 0);
                acc[i][j] = __builtin_amdgcn_mfma_f32_16x16x32_bf16(fah[i], fbl[j], acc[i][j], 0, 0, 0);
            }
        __syncthreads();
    }
    // ---- epilogue: C/D layout col=lane&15, row=quad*4+reg (m89-verified) ----
#pragma unroll
    for (int j = 0; j < 4; ++j) {
        int gn = n0 + wn + j * 16 + lm;
        float bv = bias ? bias[gn] : 0.f;
#pragma unroll
        for (int i = 0; i < 4; ++i) {
#pragma unroll
            for (int r = 0; r < 4; ++r) {
                int gm = m0 + wm + i * 16 + lq * 4 + r;
                if (gm < M) {
                    float v = acc[i][j][r] + bv;
                    if (ACT == 1) v = fmaxf(v, 0.f);
                    if (ACT == 2) v = v > 0.f ? v : expm1f(v);
                    C[(long)gm * N + gn] = v;
                }
            }
        }
    }
}

// ---- wa[k] = sum_n W[k][n] * a[n]  (grid = K blocks) ----
__global__ __launch_bounds__(256) void matvec_w(
    const float* __restrict__ W, const float* __restrict__ a,
    float* __restrict__ out, int N)
{
    int k = blockIdx.x, t = threadIdx.x;
    float s = 0.f;
    for (int n = t; n < N; n += 256) s += W[(long)k * N + n] * a[n];
#pragma unroll
    for (int o = 32; o; o >>= 1) s += __shfl_down(s, o);
    __shared__ float ls[4];
    if ((t & 63) == 0) ls[t >> 6] = s;
    __syncthreads();
    if (t == 0) out[k] = ls[0] + ls[1] + ls[2] + ls[3];
}

// ---------------- per-node attention scalars (F=256): h . wa_s, h . wa_d ----
__global__ __launch_bounds__(256) void att_scalars(
    const float* __restrict__ x, const float* __restrict__ avs,
    const float* __restrict__ avd, float* __restrict__ outs,
    float* __restrict__ outd, int F)
{
    const int i = blockIdx.x;
    const int t = threadIdx.x;
    float ps = 0.f, pd = 0.f;
    for (int f = t; f < F; f += 256) {
        float v = x[(long)i * F + f];
        ps += v * avs[f];
        pd += v * avd[f];
    }
#pragma unroll
    for (int off = 32; off; off >>= 1) {
        ps += __shfl_down(ps, off);
        pd += __shfl_down(pd, off);
    }
    __shared__ float ls[4], ld[4];
    int lane = t & 63, w = t >> 6;
    if (lane == 0) { ls[w] = ps; ld[w] = pd; }
    __syncthreads();
    if (t == 0) {
        outs[i] = ls[0] + ls[1] + ls[2] + ls[3];
        outd[i] = ld[0] + ld[1] + ld[2] + ld[3];
    }
}

__device__ __forceinline__ float lrelu(float v) {
    return v > 0.f ? v : NEG_SLOPE * v;
}

// ---------------------------- CSR build (by dst) ----------------------------
__global__ __launch_bounds__(256) void hist_kernel(
    const int* __restrict__ dst, int* __restrict__ cnt, int E, int n)
{
    int t = blockIdx.x * 256 + threadIdx.x;
    if (t >= E + n) return;
    int d = t < E ? dst[t] : (t - E);
    atomicAdd(&cnt[d], 1);
}

#define SCAN_T 1024
__global__ __launch_bounds__(SCAN_T) void scan_kernel(
    const int* __restrict__ cnt, int* __restrict__ off,
    int* __restrict__ cursor, int n)
{
    __shared__ int sums[SCAN_T];
    int t = threadIdx.x;
    int chunk = (n + SCAN_T - 1) / SCAN_T;
    int lo = t * chunk, hi = min(lo + chunk, n);
    int s = 0;
    for (int i = lo; i < hi; ++i) s += cnt[i];
    sums[t] = s;
    __syncthreads();
    for (int d = 1; d < SCAN_T; d <<= 1) {
        int v = (t >= d) ? sums[t - d] : 0;
        __syncthreads();
        sums[t] += v;
        __syncthreads();
    }
    int run = sums[t] - s;
    for (int i = lo; i < hi; ++i) {
        off[i] = run;
        cursor[i] = run;
        run += cnt[i];
    }
    if (t == SCAN_T - 1) off[n] = sums[SCAN_T - 1];
}

__global__ __launch_bounds__(256) void scatter_kernel(
    const int* __restrict__ src, const int* __restrict__ dst,
    int* __restrict__ cursor, int* __restrict__ ebuf, int E, int n)
{
    int t = blockIdx.x * 256 + threadIdx.x;
    if (t >= E + n) return;
    int s = t < E ? src[t] : (t - E);
    int d = t < E ? dst[t] : (t - E);
    int pos = atomicAdd(&cursor[d], 1);
    ebuf[pos] = s;
}

// ------------- fused softmax + aggregate, F=256 fixed -----------------------
// One block per dst. Pass 1: block max of e. Pass 2: wave w takes edges
// p = lo+w, step 4; lane reads float4 of x[src] (1KB row per wave-issue).
// Cross-wave combine via LDS. EPI: 0 = raw sum store, 1 = bias+relu.
template<int EPI>
__global__ __launch_bounds__(256) void gat_agg_kernel(
    const int* __restrict__ off, const int* __restrict__ ebuf,
    const float* __restrict__ as_, const float* __restrict__ ad_,
    const float* __restrict__ x, const float* __restrict__ bias,
    float* __restrict__ out)
{
    __shared__ float sacc[4][256];
    __shared__ float sred[8];
    int d = blockIdx.x;
    int tid = threadIdx.x;
    int w = tid >> 6, lane = tid & 63;
    int lo = off[d], hi = off[d + 1];
    float adv = ad_[d];
    // ---- pass 1: block-wide max of e ----
    float m = -INFINITY;
    for (int p = lo + tid; p < hi; p += 256)
        m = fmaxf(m, lrelu(as_[ebuf[p]] + adv));
#pragma unroll
    for (int o = 32; o; o >>= 1) m = fmaxf(m, __shfl_xor(m, o));
    if (lane == 0) sred[w] = m;
    __syncthreads();
    m = fmaxf(fmaxf(sred[0], sred[1]), fmaxf(sred[2], sred[3]));
    // ---- pass 2: per-wave edge accumulate (e is lane-uniform) ----
    float4 acc = {0.f, 0.f, 0.f, 0.f};
    float psum = 0.f;
    for (int p = lo + w; p < hi; p += 4) {
        int s = ebuf[p];
        float e = expf(lrelu(as_[s] + adv) - m);
        psum += e;
        float4 v = *(const float4*)(x + (long)s * 256 + lane * 4);
        acc.x = fmaf(e, v.x, acc.x);
        acc.y = fmaf(e, v.y, acc.y);
        acc.z = fmaf(e, v.z, acc.z);
        acc.w = fmaf(e, v.w, acc.w);
    }
    if (lane == 0) sred[4 + w] = psum;  // disjoint slots: no WAR with pass-1 reads
    *(float4*)&sacc[w][lane * 4] = acc;
    __syncthreads();
    float inv = 1.f / (sred[4] + sred[5] + sred[6] + sred[7]);
    float v = (sacc[0][tid] + sacc[1][tid] + sacc[2][tid] + sacc[3][tid]) * inv;
    if (EPI == 1) v = fmaxf(v + bias[tid], 0.f);
    out[(long)d * 256 + tid] = v;
}

// comb[i] = concat(dfin[didx[i]], cfin[cidx[i]])
__global__ __launch_bounds__(256) void gather_concat_kernel(
    const float* __restrict__ dfin, const float* __restrict__ cfin,
    const int* __restrict__ didx, const int* __restrict__ cidx,
    float* __restrict__ comb)
{
    int i = blockIdx.x;
    int t = threadIdx.x;
    int ds = didx[i], cs = cidx[i];
    comb[(long)i * 512 + t] = dfin[(long)ds * 256 + t];
    comb[(long)i * 512 + 256 + t] = cfin[(long)cs * 256 + t];
}

// out[i] = h[i] . w + b[0]
__global__ __launch_bounds__(256) void head_final_kernel(
    const float* __restrict__ h, const float* __restrict__ w,
    const float* __restrict__ b, float* __restrict__ out, int M)
{
    int gw = blockIdx.x * 4 + (threadIdx.x >> 6);
    int lane = threadIdx.x & 63;
    if (gw >= M) return;
    const float* row = h + (long)gw * 512;
    float s = 0.f;
#pragma unroll
    for (int f = lane; f < 512; f += 64) s += row[f] * w[f];
#pragma unroll
    for (int off = 32; off; off >>= 1) s += __shfl_down(s, off);
    if (lane == 0) out[gw] = s + b[0];
}

// ------------------------------ orchestration -------------------------------
static inline dim3 mfma_grid(int M, int N) { return dim3(N / 128, (M + 127) / 128); }

extern "C" void kernel_launch(void* const* d_in, const int* in_sizes, int n_in,
                              void* d_out, int out_size, void* d_ws, size_t ws_size,
                              hipStream_t stream)
{
    const float* drug_x = (const float*)d_in[0];
    const float* cell_x = (const float*)d_in[1];
    const int* d_ei = (const int*)d_in[2];
    const int* c_ei = (const int*)d_in[3];
    const int* d_idx = (const int*)d_in[4];
    const int* c_idx = (const int*)d_in[5];
    const float* dW1 = (const float*)d_in[6];
    const float* db1 = (const float*)d_in[7];
    const float* cW1 = (const float*)d_in[8];
    const float* cb1 = (const float*)d_in[9];
    const float* cW2 = (const float*)d_in[10];
    const float* cb2 = (const float*)d_in[11];
    const float* gdW = (const float*)d_in[12];
    const float* gdas = (const float*)d_in[13];
    const float* gdad = (const float*)d_in[14];
    const float* gdb = (const float*)d_in[15];
    const float* g1W = (const float*)d_in[16];
    const float* g1as = (const float*)d_in[17];
    const float* g1ad = (const float*)d_in[18];
    const float* g1b = (const float*)d_in[19];
    const float* g2W = (const float*)d_in[20];
    const float* g2as = (const float*)d_in[21];
    const float* g2ad = (const float*)d_in[22];
    const float* g2b = (const float*)d_in[23];
    const float* rW1 = (const float*)d_in[24];
    const float* rb1 = (const float*)d_in[25];
    const float* rW2 = (const float*)d_in[26];
    const float* rb2 = (const float*)d_in[27];
    const float* rW3 = (const float*)d_in[28];
    const float* rb3 = (const float*)d_in[29];

    const int ND = in_sizes[0] / 128;     // 50000
    const int NC = in_sizes[1] / 735;     // 10000
    const int ED = in_sizes[2] / 2;       // 800000
    const int EC = in_sizes[3] / 2;       // 160000
    const int NB = in_sizes[4];           // 16384

    const int* d_src = d_ei;
    const int* d_dst = d_ei + ED;
    const int* c_src = c_ei;
    const int* c_dst = c_ei + EC;

    const size_t MB = 1ull << 20;
    const size_t KB = 1024;
    char* ws = (char*)d_ws;

    // ---- weight split region [0, 9MB) ----
    size_t wo = 0;
    auto walloc = [&](size_t elems) -> unsigned short* {
        unsigned short* p = (unsigned short*)(ws + wo);
        wo += ((elems * 2 + 255) & ~(size_t)255);
        return p;
    };
    unsigned short* dW1h = walloc(256 * 128);  unsigned short* dW1l = walloc(256 * 128);
    unsigned short* cW1h = walloc(1024 * 736); unsigned short* cW1l = walloc(1024 * 736);
    unsigned short* cW2h = walloc(256 * 1024); unsigned short* cW2l = walloc(256 * 1024);
    unsigned short* gdWh = walloc(256 * 256);  unsigned short* gdWl = walloc(256 * 256);
    unsigned short* g1Wh = walloc(1024 * 256); unsigned short* g1Wl = walloc(1024 * 256);
    unsigned short* g2Wh = walloc(256 * 1024); unsigned short* g2Wl = walloc(256 * 1024);
    unsigned short* rW1h = walloc(512 * 512);  unsigned short* rW1l = walloc(512 * 512);
    unsigned short* rW2h = walloc(512 * 512);  unsigned short* rW2l = walloc(512 * 512);

    // ---- small scratch ----
    float* wa_ds  = (float*)(ws + 9 * MB);             // gdW @ gdas [256]
    float* wa_dd  = (float*)(ws + 9 * MB + 4 * KB);
    float* wa_c1s = (float*)(ws + 9 * MB + 8 * KB);    // g1W @ g1as [256]
    float* wa_c1d = (float*)(ws + 9 * MB + 12 * KB);
    float* cas    = (float*)(ws + 9 * MB + 64 * KB);   // [NC]
    float* cad    = (float*)(ws + 9 * MB + 128 * KB);
    int*   coff   = (int*)(ws + 9 * MB + 192 * KB);    // NC+1
    int*   ccur   = (int*)(ws + 9 * MB + 256 * KB);
    int*   ccnt   = (int*)(ws + 9 * MB + 320 * KB);
    int*   cebuf  = (int*)(ws + 10 * MB);              // EC+NC ints (680KB)
    float* das    = (float*)(ws + 11 * MB);            // [ND] 200KB
    float* dad    = (float*)(ws + 11 * MB + 256 * KB);
    int*   doff   = (int*)(ws + 11 * MB + 512 * KB);   // ND+1
    int*   dcur   = (int*)(ws + 11 * MB + 768 * KB);
    int*   dcnt   = (int*)(ws + 12 * MB);
    int*   debuf  = (int*)(ws + 12 * MB + 256 * KB);   // ED+ND ints (3.4MB -> ~15.7)

    // ---- big buffers (liveness-checked) ----
    float* dbuf = (float*)(ws + 16 * MB);   // d0, then dfin  [ND,256] 51.2MB -> [16,67.2)
    float* aggd = (float*)(ws + 68 * MB);   // drug agg out   [ND,256] -> [68,119.2)
    float* c0b  = (float*)(ws + 68 * MB);   // [NC,1024] 40MB (aggd dead) -> [68,108)
    float* c1b  = (float*)(ws + 108 * MB);  // [NC,256] 10MB -> [108,118)
    float* aggc = (float*)(ws + 120 * MB);  // [NC,256] 10MB -> [120,130)
    float* c2b  = (float*)(ws + 68 * MB);   // [NC,1024] 40MB (c0 dead) -> [68,108)
    float* xc2  = (float*)(ws + 108 * MB);  // [NC,256] (c1 dead) -> [108,118)
    float* cfin = (float*)(ws + 120 * MB);  // [NC,256] (aggc dead) -> [120,130)
    float* comb = (float*)(ws + 68 * MB);   // [NB,512] 32MB (c2 dead) -> [68,100)
    float* h1b  = (float*)(ws + 100 * MB);  // [NB,512] (cfin dead after gather) -> [100,132)
    float* h2b  = (float*)(ws + 68 * MB);   // [NB,512] (comb dead) -> [68,100)

    // ================= weight pre-split + wa vectors =========================
    split_transpose<<<dim3(256 / 32, 128 / 32), 256, 0, stream>>>(dW1, dW1h, dW1l, 128, 256, 128);
    split_transpose<<<dim3(1024 / 32, 736 / 32), 256, 0, stream>>>(cW1, cW1h, cW1l, 735, 1024, 736);
    split_transpose<<<dim3(256 / 32, 1024 / 32), 256, 0, stream>>>(cW2, cW2h, cW2l, 1024, 256, 1024);
    split_transpose<<<dim3(256 / 32, 256 / 32), 256, 0, stream>>>(gdW, gdWh, gdWl, 256, 256, 256);
    split_transpose<<<dim3(1024 / 32, 256 / 32), 256, 0, stream>>>(g1W, g1Wh, g1Wl, 256, 1024, 256);
    split_transpose<<<dim3(256 / 32, 1024 / 32), 256, 0, stream>>>(g2W, g2Wh, g2Wl, 1024, 256, 1024);
    split_transpose<<<dim3(512 / 32, 512 / 32), 256, 0, stream>>>(rW1, rW1h, rW1l, 512, 512, 512);
    split_transpose<<<dim3(512 / 32, 512 / 32), 256, 0, stream>>>(rW2, rW2h, rW2l, 512, 512, 512);
    matvec_w<<<256, 256, 0, stream>>>(gdW, gdas, wa_ds, 256);
    matvec_w<<<256, 256, 0, stream>>>(gdW, gdad, wa_dd, 256);
    matvec_w<<<256, 256, 0, stream>>>(g1W, g1as, wa_c1s, 1024);
    matvec_w<<<256, 256, 0, stream>>>(g1W, g1ad, wa_c1d, 1024);

    // ======================= drug path =======================
    // d0 = relu(drug_x @ dW1 + db1)
    gemm_mfma<1><<<mfma_grid(ND, 256), 256, 0, stream>>>(drug_x, dW1h, dW1l, db1, dbuf, ND, 128, 256, 128);
    // attention scalars on d0 via projected vectors:  as = d0 . (gdW a_src)
    att_scalars<<<ND, 256, 0, stream>>>(dbuf, wa_ds, wa_dd, das, dad, 256);
    hipMemsetAsync(dcnt, 0, (size_t)ND * 4, stream);
    {
        int tot = ED + ND;
        hist_kernel<<<(tot + 255) / 256, 256, 0, stream>>>(d_dst, dcnt, ED, ND);
        scan_kernel<<<1, SCAN_T, 0, stream>>>(dcnt, doff, dcur, ND);
        scatter_kernel<<<(tot + 255) / 256, 256, 0, stream>>>(d_src, d_dst, dcur, debuf, ED, ND);
        // aggd = softmax-agg of d0 rows (pre-projection; Σα(hW) == (Σαh)W)
        gat_agg_kernel<0><<<ND, 256, 0, stream>>>(doff, debuf, das, dad, dbuf, nullptr, aggd);
    }
    // dfin = relu(aggd @ gdW + gdb)
    gemm_mfma<1><<<mfma_grid(ND, 256), 256, 0, stream>>>(aggd, gdWh, gdWl, gdb, dbuf, ND, 256, 256, 256);

    // ======================= cell path =======================
    gemm_mfma<1><<<mfma_grid(NC, 1024), 256, 0, stream>>>(cell_x, cW1h, cW1l, cb1, c0b, NC, 735, 1024, 736);
    gemm_mfma<1><<<mfma_grid(NC, 256), 256, 0, stream>>>(c0b, cW2h, cW2l, cb2, c1b, NC, 1024, 256, 1024);
    // GAT1: scalars from c1 via (g1W a), aggregate 256-wide c1, then project.
    att_scalars<<<NC, 256, 0, stream>>>(c1b, wa_c1s, wa_c1d, cas, cad, 256);
    hipMemsetAsync(ccnt, 0, (size_t)NC * 4, stream);
    {
        int tot = EC + NC;
        hist_kernel<<<(tot + 255) / 256, 256, 0, stream>>>(c_dst, ccnt, EC, NC);
        scan_kernel<<<1, SCAN_T, 0, stream>>>(ccnt, coff, ccur, NC);
        scatter_kernel<<<(tot + 255) / 256, 256, 0, stream>>>(c_src, c_dst, ccur, cebuf, EC, NC);
        gat_agg_kernel<0><<<NC, 256, 0, stream>>>(coff, cebuf, cas, cad, c1b, nullptr, aggc);
    }
    // c2 = relu(aggc @ g1W + g1b)
    gemm_mfma<1><<<mfma_grid(NC, 1024), 256, 0, stream>>>(aggc, g1Wh, g1Wl, g1b, c2b, NC, 256, 1024, 256);
    // GAT2 (1024->256): project first (narrow output), then aggregate.
    gemm_mfma<0><<<mfma_grid(NC, 256), 256, 0, stream>>>(c2b, g2Wh, g2Wl, nullptr, xc2, NC, 1024, 256, 1024);
    att_scalars<<<NC, 256, 0, stream>>>(xc2, g2as, g2ad, cas, cad, 256);
    // CSR reused (same graph); bias+relu fused in agg epilogue.
    gat_agg_kernel<1><<<NC, 256, 0, stream>>>(coff, cebuf, cas, cad, xc2, g2b, cfin);

    // ======================= head =======================
    gather_concat_kernel<<<NB, 256, 0, stream>>>(dbuf, cfin, d_idx, c_idx, comb);
    gemm_mfma<2><<<mfma_grid(NB, 512), 256, 0, stream>>>(comb, rW1h, rW1l, rb1, h1b, NB, 512, 512, 512);
    gemm_mfma<2><<<mfma_grid(NB, 512), 256, 0, stream>>>(h1b, rW2h, rW2l, rb2, h2b, NB, 512, 512, 512);
    head_final_kernel<<<(NB + 3) / 4, 256, 0, stream>>>(h2b, rW3, rb3, (float*)d_out, NB);
}

// Round 5
// 1088.870 us; speedup vs baseline: 6.8324x; 1.1390x over previous
//
#include <hip/hip_runtime.h>
#include <math.h>

#define NEG_SLOPE 0.2f

typedef __attribute__((ext_vector_type(8))) short short8;
typedef __attribute__((ext_vector_type(4))) float floatx4;

// ---------------- fp32 <-> bf16 split helpers (RNE) ----------------
__device__ __forceinline__ unsigned short f2bf(float f) {
    unsigned u = __float_as_uint(f);
    u += 0x7fffu + ((u >> 16) & 1u);
    return (unsigned short)(u >> 16);
}
__device__ __forceinline__ float bf2f(unsigned short h) {
    return __uint_as_float((unsigned)h << 16);
}
__device__ __forceinline__ float lrelu(float v) {
    return v > 0.f ? v : NEG_SLOPE * v;
}

// ---------------- fused weight pre-pass: 8 jobs in one launch ----------------
struct SJob { const float* W; unsigned short* Th; unsigned short* Tl; int K, N, Kp, base; };
struct SJobs { SJob j[8]; };

__global__ __launch_bounds__(256) void split_transpose_multi(SJobs js) {
    int t = blockIdx.x;
    int ji = 0;
#pragma unroll
    for (int q = 1; q < 8; ++q) if (t >= js.j[q].base) ji = q;
    const SJob jb = js.j[ji];
    int local = t - jb.base;
    int ntiles = jb.N / 32;
    int tn = local % ntiles, tk = local / ntiles;
    int k0 = tk * 32, n0 = tn * 32;
    __shared__ float tbuf[32][33];
    int c = threadIdx.x & 31, r = threadIdx.x >> 5;
    for (int rr = r; rr < 32; rr += 8) {
        int k = k0 + rr, n = n0 + c;
        tbuf[rr][c] = (k < jb.K && n < jb.N) ? jb.W[(long)k * jb.N + n] : 0.f;
    }
    __syncthreads();
    for (int rr = r; rr < 32; rr += 8) {
        int n = n0 + rr, k = k0 + c;
        if (n < jb.N && k < jb.Kp) {
            float v = tbuf[c][rr];
            unsigned short h = f2bf(v);
            jb.Th[(long)n * jb.Kp + k] = h;
            jb.Tl[(long)n * jb.Kp + k] = f2bf(v - bf2f(h));
        }
    }
}

// ---- 4 fused matvecs: wa[k] = sum_n W[k][n]*a[n] (k in [0,256) each) ----
__global__ __launch_bounds__(256) void matvec4(
    const float* __restrict__ gdW, const float* __restrict__ gdas, const float* __restrict__ gdad,
    float* __restrict__ wds, float* __restrict__ wdd,
    const float* __restrict__ g1W, const float* __restrict__ g1as, const float* __restrict__ g1ad,
    float* __restrict__ w1s, float* __restrict__ w1d)
{
    int b = blockIdx.x;
    int sel = b >> 8, k = b & 255, t = threadIdx.x;
    const float *W, *a; float* o; int N;
    if (sel == 0)      { W = gdW; a = gdas; o = wds; N = 256; }
    else if (sel == 1) { W = gdW; a = gdad; o = wdd; N = 256; }
    else if (sel == 2) { W = g1W; a = g1as; o = w1s; N = 1024; }
    else               { W = g1W; a = g1ad; o = w1d; N = 1024; }
    float s = 0.f;
    for (int n = t; n < N; n += 256) s += W[(long)k * N + n] * a[n];
#pragma unroll
    for (int off = 32; off; off >>= 1) s += __shfl_down(s, off);
    __shared__ float ls[4];
    if ((t & 63) == 0) ls[t >> 6] = s;
    __syncthreads();
    if (t == 0) o[k] = ls[0] + ls[1] + ls[2] + ls[3];
}

// ---------------- GEMM via split-bf16 MFMA: C = act(A @ B + bias) -----------
// ASPLIT=0: A fp32 [M][K], split on the fly.  ASPLIT=1: A pre-split bf16
// planes [ceil128(M)][K] (K%32==0), staged with pure 16B loads.
// OSPLIT=0: write fp32 C.  OSPLIT=1: write bf16 hi/lo planes (for next GEMM).
template<int ACT, int ASPLIT, int OSPLIT>  // ACT: 0=none,1=relu,2=elu
__global__ __launch_bounds__(256, 2) void gemm2(
    const float* __restrict__ A,
    const unsigned short* __restrict__ Ah_g, const unsigned short* __restrict__ Al_g,
    const unsigned short* __restrict__ Bh_g, const unsigned short* __restrict__ Bl_g,
    const float* __restrict__ bias,
    float* __restrict__ C, unsigned short* __restrict__ Ch_g, unsigned short* __restrict__ Cl_g,
    int M, int K, int N, int Kp)
{
    __shared__ unsigned short Ah[128][40];
    __shared__ unsigned short Al[128][40];
    __shared__ unsigned short Bh[128][40];
    __shared__ unsigned short Bl[128][40];
    const int tid = threadIdx.x;
    const int wave = tid >> 6, lane = tid & 63;
    const int lm = lane & 15, lq = lane >> 4;
    const int wm = (wave & 1) << 6, wn = (wave >> 1) << 6;
    const int m0 = blockIdx.y * 128, n0 = blockIdx.x * 128;
    floatx4 acc[4][4];
    floatx4 zero = {0.f, 0.f, 0.f, 0.f};
#pragma unroll
    for (int i = 0; i < 4; ++i)
#pragma unroll
        for (int j = 0; j < 4; ++j) acc[i][j] = zero;

    const bool k4 = (K & 3) == 0;
    const int brow = tid >> 1, bhalf = tid & 1;

    for (int k0 = 0; k0 < K; k0 += 32) {
        if (ASPLIT) {
            // pre-split A: same staging shape as B (rows padded to 128 mult)
            long ab = (long)(m0 + brow) * K + k0 + bhalf * 16;
            uint4 a0 = *(const uint4*)(Ah_g + ab);
            uint4 a1 = *(const uint4*)(Ah_g + ab + 8);
            *(uint4*)&Ah[brow][bhalf * 16] = a0;
            *(uint4*)&Ah[brow][bhalf * 16 + 8] = a1;
            uint4 b0 = *(const uint4*)(Al_g + ab);
            uint4 b1 = *(const uint4*)(Al_g + ab + 8);
            *(uint4*)&Al[brow][bhalf * 16] = b0;
            *(uint4*)&Al[brow][bhalf * 16 + 8] = b1;
        } else {
#pragma unroll
            for (int it = 0; it < 4; ++it) {
                int slot = tid + it * 256;
                int row = slot >> 3, kq = slot & 7;
                int gm = m0 + row, kb = k0 + kq * 4;
                float v0 = 0.f, v1 = 0.f, v2 = 0.f, v3 = 0.f;
                if (gm < M) {
                    if (k4 && kb + 4 <= K) {
                        float4 t = *(const float4*)(A + (long)gm * K + kb);
                        v0 = t.x; v1 = t.y; v2 = t.z; v3 = t.w;
                    } else {
                        if (kb + 0 < K) v0 = A[(long)gm * K + kb + 0];
                        if (kb + 1 < K) v1 = A[(long)gm * K + kb + 1];
                        if (kb + 2 < K) v2 = A[(long)gm * K + kb + 2];
                        if (kb + 3 < K) v3 = A[(long)gm * K + kb + 3];
                    }
                }
                unsigned short h0 = f2bf(v0), h1 = f2bf(v1), h2 = f2bf(v2), h3 = f2bf(v3);
                unsigned short l0 = f2bf(v0 - bf2f(h0)), l1 = f2bf(v1 - bf2f(h1));
                unsigned short l2 = f2bf(v2 - bf2f(h2)), l3 = f2bf(v3 - bf2f(h3));
                uint2 ph = {(unsigned)h0 | ((unsigned)h1 << 16), (unsigned)h2 | ((unsigned)h3 << 16)};
                uint2 pl = {(unsigned)l0 | ((unsigned)l1 << 16), (unsigned)l2 | ((unsigned)l3 << 16)};
                *(uint2*)&Ah[row][kq * 4] = ph;
                *(uint2*)&Al[row][kq * 4] = pl;
            }
        }
        // ---- stage B tile [128n][32k]: pre-split, coalesced 16B loads ----
        {
            long bb = (long)(n0 + brow) * Kp + k0 + bhalf * 16;
            uint4 x0 = *(const uint4*)(Bh_g + bb);
            uint4 x1 = *(const uint4*)(Bh_g + bb + 8);
            *(uint4*)&Bh[brow][bhalf * 16] = x0;
            *(uint4*)&Bh[brow][bhalf * 16 + 8] = x1;
            uint4 y0 = *(const uint4*)(Bl_g + bb);
            uint4 y1 = *(const uint4*)(Bl_g + bb + 8);
            *(uint4*)&Bl[brow][bhalf * 16] = y0;
            *(uint4*)&Bl[brow][bhalf * 16 + 8] = y1;
        }
        __syncthreads();
        short8 fah[4], fal[4], fbh[4], fbl[4];
#pragma unroll
        for (int i = 0; i < 4; ++i) {
            fah[i] = *(const short8*)&Ah[wm + i * 16 + lm][lq * 8];
            fal[i] = *(const short8*)&Al[wm + i * 16 + lm][lq * 8];
        }
#pragma unroll
        for (int j = 0; j < 4; ++j) {
            fbh[j] = *(const short8*)&Bh[wn + j * 16 + lm][lq * 8];
            fbl[j] = *(const short8*)&Bl[wn + j * 16 + lm][lq * 8];
        }
#pragma unroll
        for (int i = 0; i < 4; ++i)
#pragma unroll
            for (int j = 0; j < 4; ++j) {
                acc[i][j] = __builtin_amdgcn_mfma_f32_16x16x32_bf16(fah[i], fbh[j], acc[i][j], 0, 0, 0);
                acc[i][j] = __builtin_amdgcn_mfma_f32_16x16x32_bf16(fal[i], fbh[j], acc[i][j], 0, 0, 0);
                acc[i][j] = __builtin_amdgcn_mfma_f32_16x16x32_bf16(fah[i], fbl[j], acc[i][j], 0, 0, 0);
            }
        __syncthreads();
    }
    // ---- epilogue: C/D layout col=lane&15, row=quad*4+reg (m89-verified) ----
#pragma unroll
    for (int j = 0; j < 4; ++j) {
        int gn = n0 + wn + j * 16 + lm;
        float bv = bias ? bias[gn] : 0.f;
#pragma unroll
        for (int i = 0; i < 4; ++i) {
#pragma unroll
            for (int r = 0; r < 4; ++r) {
                int gm = m0 + wm + i * 16 + lq * 4 + r;
                if (gm < M) {
                    float v = acc[i][j][r] + bv;
                    if (ACT == 1) v = fmaxf(v, 0.f);
                    if (ACT == 2) v = v > 0.f ? v : expm1f(v);
                    long o = (long)gm * N + gn;
                    if (OSPLIT) {
                        unsigned short h = f2bf(v);
                        Ch_g[o] = h;
                        Cl_g[o] = f2bf(v - bf2f(h));
                    } else {
                        C[o] = v;
                    }
                }
            }
        }
    }
}

// ---------------- per-node attention scalars (F=256) ----------------
__global__ __launch_bounds__(256) void att_scalars(
    const float* __restrict__ x, const float* __restrict__ avs,
    const float* __restrict__ avd, float* __restrict__ outs,
    float* __restrict__ outd, int F)
{
    const int i = blockIdx.x;
    const int t = threadIdx.x;
    float ps = 0.f, pd = 0.f;
    for (int f = t; f < F; f += 256) {
        float v = x[(long)i * F + f];
        ps += v * avs[f];
        pd += v * avd[f];
    }
#pragma unroll
    for (int off = 32; off; off >>= 1) {
        ps += __shfl_down(ps, off);
        pd += __shfl_down(pd, off);
    }
    __shared__ float ls[4], ld[4];
    int lane = t & 63, w = t >> 6;
    if (lane == 0) { ls[w] = ps; ld[w] = pd; }
    __syncthreads();
    if (t == 0) {
        outs[i] = ls[0] + ls[1] + ls[2] + ls[3];
        outd[i] = ld[0] + ld[1] + ld[2] + ld[3];
    }
}

// ---------------------------- CSR build (by dst) ----------------------------
__global__ __launch_bounds__(256) void hist_kernel(
    const int* __restrict__ dst, int* __restrict__ cnt, int E, int n)
{
    int t = blockIdx.x * 256 + threadIdx.x;
    if (t >= E + n) return;
    int d = t < E ? dst[t] : (t - E);
    atomicAdd(&cnt[d], 1);
}

#define SCAN_T 1024
__global__ __launch_bounds__(SCAN_T) void scan_kernel(
    const int* __restrict__ cnt, int* __restrict__ off,
    int* __restrict__ cursor, int n)
{
    __shared__ int sums[SCAN_T];
    int t = threadIdx.x;
    int chunk = (n + SCAN_T - 1) / SCAN_T;
    int lo = t * chunk, hi = min(lo + chunk, n);
    int s = 0;
    for (int i = lo; i < hi; ++i) s += cnt[i];
    sums[t] = s;
    __syncthreads();
    for (int d = 1; d < SCAN_T; d <<= 1) {
        int v = (t >= d) ? sums[t - d] : 0;
        __syncthreads();
        sums[t] += v;
        __syncthreads();
    }
    int run = sums[t] - s;
    for (int i = lo; i < hi; ++i) {
        off[i] = run;
        cursor[i] = run;
        run += cnt[i];
    }
    if (t == SCAN_T - 1) off[n] = sums[SCAN_T - 1];
}

__global__ __launch_bounds__(256) void scatter_kernel(
    const int* __restrict__ src, const int* __restrict__ dst,
    int* __restrict__ cursor, int* __restrict__ ebuf, int E, int n)
{
    int t = blockIdx.x * 256 + threadIdx.x;
    if (t >= E + n) return;
    int s = t < E ? src[t] : (t - E);
    int d = t < E ? dst[t] : (t - E);
    int pos = atomicAdd(&cursor[d], 1);
    ebuf[pos] = s;
}

// ------------- fused softmax + aggregate, F=256 fixed -----------------------
// One block/dst. Edge (src, exp) staged in LDS chunks -> no serial
// ebuf->address dependency; waves consume with 2x-unrolled row loads.
// EPI 0: write bf16 hi/lo split planes (feeds GEMM). EPI 1: fp32 bias+relu.
template<int EPI>
__global__ __launch_bounds__(256) void gat_agg2(
    const int* __restrict__ off, const int* __restrict__ ebuf,
    const float* __restrict__ as_, const float* __restrict__ ad_,
    const float* __restrict__ x, const float* __restrict__ bias,
    float* __restrict__ outF, unsigned short* __restrict__ outH,
    unsigned short* __restrict__ outL)
{
    __shared__ float sacc[4][256];
    __shared__ int   sS[128];
    __shared__ float sE[128];
    __shared__ float sred[8];
    int d = blockIdx.x, tid = threadIdx.x;
    int w = tid >> 6, lane = tid & 63;
    int lo = off[d], hi = off[d + 1], ne = hi - lo;
    float adv = ad_[d];
    const float* xb = x + lane * 4;
    float4 acc0 = {0.f, 0.f, 0.f, 0.f}, acc1 = {0.f, 0.f, 0.f, 0.f};
    float psum = 0.f;

    if (ne <= 128) {
        // ---- fast path: single stage, one as_ gather per edge ----
        if (tid < ne) {
            int s = ebuf[lo + tid];
            sS[tid] = s;
            sE[tid] = lrelu(as_[s] + adv);
        }
        __syncthreads();
        float m = (tid < ne) ? sE[tid] : -INFINITY;
#pragma unroll
        for (int o = 32; o; o >>= 1) m = fmaxf(m, __shfl_xor(m, o));
        if (lane == 0) sred[w] = m;
        __syncthreads();
        m = fmaxf(fmaxf(sred[0], sred[1]), fmaxf(sred[2], sred[3]));
        if (tid < ne) sE[tid] = expf(sE[tid] - m);
        __syncthreads();
        int i = w;
        for (; i + 4 < ne; i += 8) {
            int s0 = sS[i], s1 = sS[i + 4];
            float e0 = sE[i], e1 = sE[i + 4];
            float4 v0 = *(const float4*)(xb + (long)s0 * 256);
            float4 v1 = *(const float4*)(xb + (long)s1 * 256);
            psum += e0; psum += e1;
            acc0.x = fmaf(e0, v0.x, acc0.x); acc0.y = fmaf(e0, v0.y, acc0.y);
            acc0.z = fmaf(e0, v0.z, acc0.z); acc0.w = fmaf(e0, v0.w, acc0.w);
            acc1.x = fmaf(e1, v1.x, acc1.x); acc1.y = fmaf(e1, v1.y, acc1.y);
            acc1.z = fmaf(e1, v1.z, acc1.z); acc1.w = fmaf(e1, v1.w, acc1.w);
        }
        if (i < ne) {
            int s0 = sS[i];
            float e0 = sE[i];
            float4 v0 = *(const float4*)(xb + (long)s0 * 256);
            psum += e0;
            acc0.x = fmaf(e0, v0.x, acc0.x); acc0.y = fmaf(e0, v0.y, acc0.y);
            acc0.z = fmaf(e0, v0.z, acc0.z); acc0.w = fmaf(e0, v0.w, acc0.w);
        }
    } else {
        // ---- general path: global max, then chunked stage+consume ----
        float m = -INFINITY;
        for (int p = lo + tid; p < hi; p += 256)
            m = fmaxf(m, lrelu(as_[ebuf[p]] + adv));
#pragma unroll
        for (int o = 32; o; o >>= 1) m = fmaxf(m, __shfl_xor(m, o));
        if (lane == 0) sred[w] = m;
        __syncthreads();
        m = fmaxf(fmaxf(sred[0], sred[1]), fmaxf(sred[2], sred[3]));
        for (int c = lo; c < hi; c += 128) {
            int cn = min(128, hi - c);
            __syncthreads();
            if (tid < cn) {
                int s = ebuf[c + tid];
                sS[tid] = s;
                sE[tid] = expf(lrelu(as_[s] + adv) - m);
            }
            __syncthreads();
            int i = w;
            for (; i + 4 < cn; i += 8) {
                int s0 = sS[i], s1 = sS[i + 4];
                float e0 = sE[i], e1 = sE[i + 4];
                float4 v0 = *(const float4*)(xb + (long)s0 * 256);
                float4 v1 = *(const float4*)(xb + (long)s1 * 256);
                psum += e0; psum += e1;
                acc0.x = fmaf(e0, v0.x, acc0.x); acc0.y = fmaf(e0, v0.y, acc0.y);
                acc0.z = fmaf(e0, v0.z, acc0.z); acc0.w = fmaf(e0, v0.w, acc0.w);
                acc1.x = fmaf(e1, v1.x, acc1.x); acc1.y = fmaf(e1, v1.y, acc1.y);
                acc1.z = fmaf(e1, v1.z, acc1.z); acc1.w = fmaf(e1, v1.w, acc1.w);
            }
            if (i < cn) {
                int s0 = sS[i];
                float e0 = sE[i];
                float4 v0 = *(const float4*)(xb + (long)s0 * 256);
                psum += e0;
                acc0.x = fmaf(e0, v0.x, acc0.x); acc0.y = fmaf(e0, v0.y, acc0.y);
                acc0.z = fmaf(e0, v0.z, acc0.z); acc0.w = fmaf(e0, v0.w, acc0.w);
            }
        }
    }
    acc0.x += acc1.x; acc0.y += acc1.y; acc0.z += acc1.z; acc0.w += acc1.w;
    if (lane == 0) sred[4 + w] = psum;
    *(float4*)&sacc[w][lane * 4] = acc0;
    __syncthreads();
    float inv = 1.f / (sred[4] + sred[5] + sred[6] + sred[7]);
    float v = (sacc[0][tid] + sacc[1][tid] + sacc[2][tid] + sacc[3][tid]) * inv;
    long o = (long)d * 256 + tid;
    if (EPI == 1) {
        outF[o] = fmaxf(v + bias[tid], 0.f);
    } else {
        unsigned short h = f2bf(v);
        outH[o] = h;
        outL[o] = f2bf(v - bf2f(h));
    }
}

// comb[i] = concat(dfin[didx[i]], cfin[cidx[i]]) -> split bf16 planes
__global__ __launch_bounds__(256) void gather_concat_split(
    const float* __restrict__ dfin, const float* __restrict__ cfin,
    const int* __restrict__ didx, const int* __restrict__ cidx,
    unsigned short* __restrict__ combH, unsigned short* __restrict__ combL)
{
    int i = blockIdx.x;
    int t = threadIdx.x;
    float v1 = dfin[(long)didx[i] * 256 + t];
    float v2 = cfin[(long)cidx[i] * 256 + t];
    long b = (long)i * 512;
    unsigned short h1 = f2bf(v1);
    combH[b + t] = h1;
    combL[b + t] = f2bf(v1 - bf2f(h1));
    unsigned short h2 = f2bf(v2);
    combH[b + 256 + t] = h2;
    combL[b + 256 + t] = f2bf(v2 - bf2f(h2));
}

// out[i] = h[i] . w + b[0]
__global__ __launch_bounds__(256) void head_final_kernel(
    const float* __restrict__ h, const float* __restrict__ w,
    const float* __restrict__ b, float* __restrict__ out, int M)
{
    int gw = blockIdx.x * 4 + (threadIdx.x >> 6);
    int lane = threadIdx.x & 63;
    if (gw >= M) return;
    const float* row = h + (long)gw * 512;
    float s = 0.f;
#pragma unroll
    for (int f = lane; f < 512; f += 64) s += row[f] * w[f];
#pragma unroll
    for (int off = 32; off; off >>= 1) s += __shfl_down(s, off);
    if (lane == 0) out[gw] = s + b[0];
}

// ------------------------------ orchestration -------------------------------
static inline dim3 mfma_grid(int M, int N) { return dim3(N / 128, (M + 127) / 128); }

extern "C" void kernel_launch(void* const* d_in, const int* in_sizes, int n_in,
                              void* d_out, int out_size, void* d_ws, size_t ws_size,
                              hipStream_t stream)
{
    const float* drug_x = (const float*)d_in[0];
    const float* cell_x = (const float*)d_in[1];
    const int* d_ei = (const int*)d_in[2];
    const int* c_ei = (const int*)d_in[3];
    const int* d_idx = (const int*)d_in[4];
    const int* c_idx = (const int*)d_in[5];
    const float* dW1 = (const float*)d_in[6];
    const float* db1 = (const float*)d_in[7];
    const float* cW1 = (const float*)d_in[8];
    const float* cb1 = (const float*)d_in[9];
    const float* cW2 = (const float*)d_in[10];
    const float* cb2 = (const float*)d_in[11];
    const float* gdW = (const float*)d_in[12];
    const float* gdas = (const float*)d_in[13];
    const float* gdad = (const float*)d_in[14];
    const float* gdb = (const float*)d_in[15];
    const float* g1W = (const float*)d_in[16];
    const float* g1as = (const float*)d_in[17];
    const float* g1ad = (const float*)d_in[18];
    const float* g1b = (const float*)d_in[19];
    const float* g2W = (const float*)d_in[20];
    const float* g2as = (const float*)d_in[21];
    const float* g2ad = (const float*)d_in[22];
    const float* g2b = (const float*)d_in[23];
    const float* rW1 = (const float*)d_in[24];
    const float* rb1 = (const float*)d_in[25];
    const float* rW2 = (const float*)d_in[26];
    const float* rb2 = (const float*)d_in[27];
    const float* rW3 = (const float*)d_in[28];
    const float* rb3 = (const float*)d_in[29];

    const int ND = in_sizes[0] / 128;     // 50000
    const int NC = in_sizes[1] / 735;     // 10000
    const int ED = in_sizes[2] / 2;       // 800000
    const int EC = in_sizes[3] / 2;       // 160000
    const int NB = in_sizes[4];           // 16384

    const int* d_src = d_ei;
    const int* d_dst = d_ei + ED;
    const int* c_src = c_ei;
    const int* c_dst = c_ei + EC;

    const size_t MB = 1ull << 20;
    const size_t KB = 1024;
    char* ws = (char*)d_ws;

    // ---- weight split region [0, 9MB) ----
    size_t wo = 0;
    auto walloc = [&](size_t elems) -> unsigned short* {
        unsigned short* p = (unsigned short*)(ws + wo);
        wo += ((elems * 2 + 255) & ~(size_t)255);
        return p;
    };
    unsigned short* dW1h = walloc(256 * 128);  unsigned short* dW1l = walloc(256 * 128);
    unsigned short* cW1h = walloc(1024 * 736); unsigned short* cW1l = walloc(1024 * 736);
    unsigned short* cW2h = walloc(256 * 1024); unsigned short* cW2l = walloc(256 * 1024);
    unsigned short* gdWh = walloc(256 * 256);  unsigned short* gdWl = walloc(256 * 256);
    unsigned short* g1Wh = walloc(1024 * 256); unsigned short* g1Wl = walloc(1024 * 256);
    unsigned short* g2Wh = walloc(256 * 1024); unsigned short* g2Wl = walloc(256 * 1024);
    unsigned short* rW1h = walloc(512 * 512);  unsigned short* rW1l = walloc(512 * 512);
    unsigned short* rW2h = walloc(512 * 512);  unsigned short* rW2l = walloc(512 * 512);

    // ---- small scratch [9, 16MB) ----
    float* wa_ds  = (float*)(ws + 9 * MB);
    float* wa_dd  = (float*)(ws + 9 * MB + 4 * KB);
    float* wa_c1s = (float*)(ws + 9 * MB + 8 * KB);
    float* wa_c1d = (float*)(ws + 9 * MB + 12 * KB);
    float* cas    = (float*)(ws + 9 * MB + 64 * KB);
    float* cad    = (float*)(ws + 9 * MB + 128 * KB);
    int*   coff   = (int*)(ws + 9 * MB + 192 * KB);
    int*   ccur   = (int*)(ws + 9 * MB + 256 * KB);
    int*   ccnt   = (int*)(ws + 9 * MB + 320 * KB);
    int*   cebuf  = (int*)(ws + 10 * MB);              // EC+NC ints
    float* das    = (float*)(ws + 11 * MB);
    float* dad    = (float*)(ws + 11 * MB + 256 * KB);
    int*   doff   = (int*)(ws + 11 * MB + 512 * KB);
    int*   dcur   = (int*)(ws + 11 * MB + 768 * KB);
    int*   dcnt   = (int*)(ws + 12 * MB);
    int*   debuf  = (int*)(ws + 12 * MB + 256 * KB);   // ED+ND ints -> ends ~15.7MB

    // ---- big buffers (liveness-checked; split planes padded to 128 rows) ----
    float* dbuf  = (float*)(ws + 16 * MB);             // d0 then dfin [ND,256] [16,65)
    unsigned short* aggdh = (unsigned short*)(ws + 68 * MB);  // [50048,256] [68,92.5)
    unsigned short* aggdl = (unsigned short*)(ws + 93 * MB);  // [93,117.5)
    unsigned short* c0h = (unsigned short*)(ws + 68 * MB);    // [10112,1024] [68,87.8)
    unsigned short* c0l = (unsigned short*)(ws + 88 * MB);    // [88,107.8)
    float* c1b   = (float*)(ws + 108 * MB);            // [NC,256] [108,117.8)
    unsigned short* aggch = (unsigned short*)(ws + 118 * MB); // [10112,256] [118,123)
    unsigned short* aggcl = (unsigned short*)(ws + 124 * MB); // [124,129)
    unsigned short* c2h = (unsigned short*)(ws + 68 * MB);    // [68,87.8)  (c0 dead)
    unsigned short* c2l = (unsigned short*)(ws + 88 * MB);    // [88,107.8)
    float* xc2   = (float*)(ws + 108 * MB);            // [108,117.8)  (c1 dead)
    float* cfin  = (float*)(ws + 118 * MB);            // [118,127.8)  (aggc dead)
    unsigned short* combh = (unsigned short*)(ws + 68 * MB);  // [16384,512] [68,84)
    unsigned short* combl = (unsigned short*)(ws + 85 * MB);  // [85,101)
    unsigned short* h1h = (unsigned short*)(ws + 102 * MB);   // [102,118)
    unsigned short* h1l = (unsigned short*)(ws + 119 * MB);   // [119,135)
    float* h2b   = (float*)(ws + 16 * MB);             // [NB,512] [16,48)  (dfin dead)

    // ================= fused prepass: 8 splits + 4 matvecs ===================
    SJobs js;
    js.j[0] = {dW1, dW1h, dW1l, 128, 256, 128, 0};
    js.j[1] = {cW1, cW1h, cW1l, 735, 1024, 736, 32};
    js.j[2] = {cW2, cW2h, cW2l, 1024, 256, 1024, 768};
    js.j[3] = {gdW, gdWh, gdWl, 256, 256, 256, 1024};
    js.j[4] = {g1W, g1Wh, g1Wl, 256, 1024, 256, 1088};
    js.j[5] = {g2W, g2Wh, g2Wl, 1024, 256, 1024, 1344};
    js.j[6] = {rW1, rW1h, rW1l, 512, 512, 512, 1600};
    js.j[7] = {rW2, rW2h, rW2l, 512, 512, 512, 1856};
    split_transpose_multi<<<2112, 256, 0, stream>>>(js);
    matvec4<<<1024, 256, 0, stream>>>(gdW, gdas, gdad, wa_ds, wa_dd,
                                      g1W, g1as, g1ad, wa_c1s, wa_c1d);

    // ======================= drug path =======================
    // d0 = relu(drug_x @ dW1 + db1) -> fp32 (feeds att_scalars + agg)
    gemm2<1, 0, 0><<<mfma_grid(ND, 256), 256, 0, stream>>>(
        drug_x, nullptr, nullptr, dW1h, dW1l, db1, dbuf, nullptr, nullptr, ND, 128, 256, 128);
    att_scalars<<<ND, 256, 0, stream>>>(dbuf, wa_ds, wa_dd, das, dad, 256);
    hipMemsetAsync(dcnt, 0, (size_t)ND * 4, stream);
    {
        int tot = ED + ND;
        hist_kernel<<<(tot + 255) / 256, 256, 0, stream>>>(d_dst, dcnt, ED, ND);
        scan_kernel<<<1, SCAN_T, 0, stream>>>(dcnt, doff, dcur, ND);
        scatter_kernel<<<(tot + 255) / 256, 256, 0, stream>>>(d_src, d_dst, dcur, debuf, ED, ND);
        // aggd (split planes) = softmax-agg of d0 rows
        gat_agg2<0><<<ND, 256, 0, stream>>>(doff, debuf, das, dad, dbuf, nullptr,
                                            nullptr, aggdh, aggdl);
    }
    // dfin = relu(aggd @ gdW + gdb) -> fp32 (feeds gather)
    gemm2<1, 1, 0><<<mfma_grid(ND, 256), 256, 0, stream>>>(
        nullptr, aggdh, aggdl, gdWh, gdWl, gdb, dbuf, nullptr, nullptr, ND, 256, 256, 256);

    // ======================= cell path =======================
    // c0 = relu(cell_x @ cW1 + cb1) -> split (feeds cW2 GEMM only)
    gemm2<1, 0, 1><<<mfma_grid(NC, 1024), 256, 0, stream>>>(
        cell_x, nullptr, nullptr, cW1h, cW1l, cb1, nullptr, c0h, c0l, NC, 735, 1024, 736);
    // c1 = relu(c0 @ cW2 + cb2) -> fp32 (feeds att_scalars + agg)
    gemm2<1, 1, 0><<<mfma_grid(NC, 256), 256, 0, stream>>>(
        nullptr, c0h, c0l, cW2h, cW2l, cb2, c1b, nullptr, nullptr, NC, 1024, 256, 1024);
    att_scalars<<<NC, 256, 0, stream>>>(c1b, wa_c1s, wa_c1d, cas, cad, 256);
    hipMemsetAsync(ccnt, 0, (size_t)NC * 4, stream);
    {
        int tot = EC + NC;
        hist_kernel<<<(tot + 255) / 256, 256, 0, stream>>>(c_dst, ccnt, EC, NC);
        scan_kernel<<<1, SCAN_T, 0, stream>>>(ccnt, coff, ccur, NC);
        scatter_kernel<<<(tot + 255) / 256, 256, 0, stream>>>(c_src, c_dst, ccur, cebuf, EC, NC);
        gat_agg2<0><<<NC, 256, 0, stream>>>(coff, cebuf, cas, cad, c1b, nullptr,
                                            nullptr, aggch, aggcl);
    }
    // c2 = relu(aggc @ g1W + g1b) -> split (feeds g2W GEMM only)
    gemm2<1, 1, 1><<<mfma_grid(NC, 1024), 256, 0, stream>>>(
        nullptr, aggch, aggcl, g1Wh, g1Wl, g1b, nullptr, c2h, c2l, NC, 256, 1024, 256);
    // xc2 = c2 @ g2W -> fp32 (feeds att_scalars + agg)
    gemm2<0, 1, 0><<<mfma_grid(NC, 256), 256, 0, stream>>>(
        nullptr, c2h, c2l, g2Wh, g2Wl, nullptr, xc2, nullptr, nullptr, NC, 1024, 256, 1024);
    att_scalars<<<NC, 256, 0, stream>>>(xc2, g2as, g2ad, cas, cad, 256);
    // CSR reused (same graph); bias+relu fused, fp32 out.
    gat_agg2<1><<<NC, 256, 0, stream>>>(coff, cebuf, cas, cad, xc2, g2b,
                                        cfin, nullptr, nullptr);

    // ======================= head =======================
    gather_concat_split<<<NB, 256, 0, stream>>>(dbuf, cfin, d_idx, c_idx, combh, combl);
    // h1 = elu(comb @ rW1 + rb1) -> split (feeds rW2 only)
    gemm2<2, 1, 1><<<mfma_grid(NB, 512), 256, 0, stream>>>(
        nullptr, combh, combl, rW1h, rW1l, rb1, nullptr, h1h, h1l, NB, 512, 512, 512);
    // h2 = elu(h1 @ rW2 + rb2) -> fp32 (feeds head matvec)
    gemm2<2, 1, 0><<<mfma_grid(NB, 512), 256, 0, stream>>>(
        nullptr, h1h, h1l, rW2h, rW2l, rb2, h2b, nullptr, nullptr, NB, 512, 512, 512);
    head_final_kernel<<<(NB + 3) / 4, 256, 0, stream>>>(h2b, rW3, rb3, (float*)d_out, NB);
}